// Round 5
// baseline (499.771 us; speedup 1.0000x reference)
//
#include <hip/hip_runtime.h>
#include <math.h>

#define Nn 120000
#define Kk 8
#define Dd 64
#define Mm 100000
#define Pp 16
#define HGg 32
#define HDd 96
#define CAP 48   // per-voxel bucket capacity; Poisson(9.6) max ~31, P(>=48)~1e-23
#define LUTB 12  // prefix bits for 2-level search (keys < 2^30)

typedef __attribute__((ext_vector_type(8))) short bf16x8;
typedef __attribute__((ext_vector_type(4))) float f32x4;

__device__ __forceinline__ float sigmoidf_(float x) { return 1.f / (1.f + __expf(-x)); }
__device__ __forceinline__ float tanh_fast(float x) {
    float e = __expf(2.f * x);          // inf for big x -> 1; 0 for very neg -> -1
    return 1.f - 2.f / (e + 1.f);
}
// f32 -> bf16 round-to-nearest-even
__device__ __forceinline__ short f2bf(float f) {
    unsigned u = __float_as_uint(f);
    unsigned r = (u + 0x7fffu + ((u >> 16) & 1u)) >> 16;
    return (short)r;
}

// -- K0: Zall = normalize(z@Wz.T); cdot[m] = c[m].w; search LUT over keys ----
__global__ __launch_bounds__(256) void k0_projz(const float* __restrict__ z,
                                                const float* __restrict__ Wz,
                                                const float* __restrict__ centers,
                                                const float* __restrict__ w_delta,
                                                const int* __restrict__ keys,
                                                float* __restrict__ Zall,
                                                float* __restrict__ cdot,
                                                int* __restrict__ lut) {
    int m = blockIdx.x * 256 + threadIdx.x;
    if (m >= Mm) return;
    // 2-level search LUT: lut[p] = lower_bound(keys, p << (30-LUTB)), p in [0,4096]
    if (m <= (1 << LUTB)) {
        int target = m << (30 - LUTB);
        int lo = 0, hi = Mm;
        while (lo < hi) {
            int mid = (lo + hi) >> 1;
            if (keys[mid] < target) lo = mid + 1; else hi = mid;
        }
        lut[m] = lo;
    }
    const float4* zr = (const float4*)(z + (size_t)m * Dd);
    float acc[Pp];
#pragma unroll
    for (int p = 0; p < Pp; p++) acc[p] = 0.f;
    for (int d4 = 0; d4 < 16; ++d4) {
        float4 f4 = zr[d4];
#pragma unroll
        for (int p = 0; p < Pp; p++) {
            const float* w = Wz + p * Dd + d4 * 4;   // wave-uniform -> s_load
            acc[p] = fmaf(f4.x, w[0], acc[p]);
            acc[p] = fmaf(f4.y, w[1], acc[p]);
            acc[p] = fmaf(f4.z, w[2], acc[p]);
            acc[p] = fmaf(f4.w, w[3], acc[p]);
        }
    }
    float ss = 0.f;
#pragma unroll
    for (int p = 0; p < Pp; p++) ss = fmaf(acc[p], acc[p], ss);
    float inv = 1.f / (sqrtf(ss) + 1e-6f);
    float4* o = (float4*)(Zall + (size_t)m * Pp);
#pragma unroll
    for (int q = 0; q < 4; q++) {
        float4 v;
        v.x = acc[4 * q] * inv;
        v.y = acc[4 * q + 1] * inv;
        v.z = acc[4 * q + 2] * inv;
        v.w = acc[4 * q + 3] * inv;
        o[q] = v;
    }
    // cdot: dot(centers[m], w_delta)  (p-c).w+b == p.w - cdot + b
    cdot[m] = centers[3 * m] * w_delta[0] + centers[3 * m + 1] * w_delta[1]
            + centers[3 * m + 2] * w_delta[2];
}

// --- K1: 4 lanes per point. hash + LUT-accelerated search + vacc atomic;
//         Fp via group-split dots; 2 candidates/lane; group softmax; insert --
__global__ __launch_bounds__(256) void k1_route(const float* __restrict__ pts,
                                                const float* __restrict__ f_pts,
                                                const float* __restrict__ Wf,
                                                const float* __restrict__ w_delta,
                                                const float* __restrict__ b_delta,
                                                const float* __restrict__ log_temp,
                                                const int* __restrict__ keys,
                                                const int* __restrict__ cand,
                                                const float* __restrict__ Zall,
                                                const float* __restrict__ cdot,
                                                const int* __restrict__ lut,
                                                float* __restrict__ wbuf,
                                                float* __restrict__ vacc,
                                                int* __restrict__ cnt,
                                                int* __restrict__ rec) {
    int g = threadIdx.x & 3;                         // lane-in-group
    int n = blockIdx.x * 64 + (threadIdx.x >> 2);    // grid = 1875 exact

    float px = pts[3 * n], py = pts[3 * n + 1], pz = pts[3 * n + 2];

    // candidate ids early (ILP): lane handles k = 2g, 2g+1
    int2 myid = ((const int2*)(cand + (size_t)n * Kk))[g];

    // IEEE f32 divide then floor, matching the reference exactly
    int ix = (int)floorf(px / 0.1f);
    int iy = (int)floorf(py / 0.1f);
    int iz = (int)floorf(pz / 0.1f);
    int h = ((ix + 512) << 20) ^ ((iy + 512) << 10) ^ (iz + 512);
    // lower_bound via prefix LUT (h in [0,2^30)): ~24-key segment -> ~5 hops
    int pfx = h >> (30 - LUTB);
    int lo = lut[pfx], hi = lut[pfx + 1];
    while (lo < hi) {
        int mid = (lo + hi) >> 1;
        if (keys[mid] < h) lo = mid + 1; else hi = mid;
    }
    int vi = lo < (Mm - 1) ? lo : (Mm - 1);
    if (g == 0) atomicAdd(vacc + vi, 0.5f);

    // ---- Fp partial dots over this lane's 16-float quarter ----
    const float4* fr = (const float4*)(f_pts + (size_t)n * Dd + g * 16);
    float4 q0 = fr[0], q1 = fr[1], q2 = fr[2], q3 = fr[3];
    float fp[Pp];
#pragma unroll
    for (int p = 0; p < Pp; p++) {
        const float4* w = (const float4*)(Wf + (size_t)p * Dd + g * 16);
        float4 w0 = w[0], w1 = w[1], w2 = w[2], w3 = w[3];
        float s = q0.x * w0.x + q0.y * w0.y + q0.z * w0.z + q0.w * w0.w;
        s += q1.x * w1.x + q1.y * w1.y + q1.z * w1.z + q1.w * w1.w;
        s += q2.x * w2.x + q2.y * w2.y + q2.z * w2.z + q2.w * w2.w;
        s += q3.x * w3.x + q3.y * w3.y + q3.z * w3.z + q3.w * w3.w;
        fp[p] = s;
    }
    // group-reduce: every lane gets the full 16-dim projection
#pragma unroll
    for (int p = 0; p < Pp; p++) {
        fp[p] += __shfl_xor(fp[p], 1, 64);
        fp[p] += __shfl_xor(fp[p], 2, 64);
    }
    float ss = 0.f;
#pragma unroll
    for (int p = 0; p < Pp; p++) ss = fmaf(fp[p], fp[p], ss);
    float inv = 1.f / (sqrtf(ss) + 1e-6f);
#pragma unroll
    for (int p = 0; p < Pp; p++) fp[p] *= inv;

    float et = expf(log_temp[0]);
    float pdot = px * w_delta[0] + py * w_delta[1] + pz * w_delta[2] + b_delta[0];

    // ---- this lane's 2 candidates ----
    int ids[2] = {myid.x, myid.y};
    float sims[2];
#pragma unroll
    for (int t = 0; t < 2; t++) {
        int id = ids[t];
        const float4* zp = (const float4*)(Zall + (size_t)id * Pp);
        float4 z0 = zp[0], z1 = zp[1], z2 = zp[2], z3 = zp[3];
        float core = fp[0] * z0.x + fp[1] * z0.y + fp[2] * z0.z + fp[3] * z0.w;
        core += fp[4] * z1.x + fp[5] * z1.y + fp[6] * z1.z + fp[7] * z1.w;
        core += fp[8] * z2.x + fp[9] * z2.y + fp[10] * z2.z + fp[11] * z2.w;
        core += fp[12] * z3.x + fp[13] * z3.y + fp[14] * z3.z + fp[15] * z3.w;
        float dt = pdot - cdot[id];
        sims[t] = et * (core + dt) / 0.3f;
    }
    // softmax over the 8 sims spread 2/lane across the 4-lane group
    float mx = fmaxf(sims[0], sims[1]);
    mx = fmaxf(mx, __shfl_xor(mx, 1, 64));
    mx = fmaxf(mx, __shfl_xor(mx, 2, 64));
    float e0 = __expf(sims[0] - mx), e1 = __expf(sims[1] - mx);
    float se = e0 + e1;
    se += __shfl_xor(se, 1, 64);
    se += __shfl_xor(se, 2, 64);
    float isum = 1.f / se;
    float w0 = e0 * isum, w1 = e1 * isum;
    ((float2*)(wbuf + (size_t)n * Kk))[g] = make_float2(w0, w1);

    // bucket insert (2 per lane); nt stores avoid write-allocate RFO
    int p0 = atomicAdd(cnt + ids[0], 1);
    if (p0 < CAP)
        __builtin_nontemporal_store((n << 3) | (2 * g), rec + (size_t)ids[0] * CAP + p0);
    int p1 = atomicAdd(cnt + ids[1], 1);
    if (p1 < CAP)
        __builtin_nontemporal_store((n << 3) | (2 * g + 1), rec + (size_t)ids[1] * CAP + p1);
}

// ---------------- K_pack: weights -> bf16 MFMA B-fragment layout ------------
// frag f, lane l: 8 bf16 = W[o = t*16 + (l&15)][k = c*32 + (l>>4)*8 + j]
__global__ __launch_bounds__(256) void k_pack(const float* __restrict__ Wg1,
                                              const float* __restrict__ W_ih,
                                              const float* __restrict__ W_hh,
                                              const float* __restrict__ Wd1,
                                              const float* __restrict__ Wd2,
                                              short* __restrict__ wsW) {
    int idx = blockIdx.x * 256 + threadIdx.x;
    if (idx >= 86 * 64) return;
    int f = idx >> 6, lane = idx & 63;
    int lrow = lane & 15, lhi = lane >> 4;
    const float* src;
    int t, c, K;
    if (f < 8)       { int g = f;      t = g >> 2; c = g & 3;  src = Wg1;  K = 128; }
    else if (f < 32) { int g = f - 8;  t = g >> 1; c = g & 1;  src = W_ih; K = 64; }
    else if (f < 56) { int g = f - 32; t = g >> 1; c = g & 1;  src = W_hh; K = 64; }
    else if (f < 68) { int g = f - 56; t = g >> 1; c = g & 1;  src = Wd1;  K = 64; }
    else             { int g = f - 68; t = g / 3;  c = g % 3;  src = Wd2;  K = 96; }
    int o = t * 16 + lrow;
    int k0 = c * 32 + lhi * 8;
    short* dst = wsW + ((size_t)f * 64 + lane) * 8;
#pragma unroll
    for (int j = 0; j < 8; j++) dst[j] = f2bf(src[(size_t)o * K + k0 + j]);
}

// ---- K3: FUSED per-voxel gather-reduce + MFMA pipeline, wave/16 voxels -----
__global__ __launch_bounds__(256) void k3_mfma(const float* __restrict__ z_latent,
                                               const float* __restrict__ f_pts,
                                               const float* __restrict__ wbuf,
                                               const int* __restrict__ cnt,
                                               const int* __restrict__ rec,
                                               const short* __restrict__ wsW,
                                               const float* __restrict__ bg1,
                                               const float* __restrict__ Wg2,
                                               const float* __restrict__ bg2,
                                               const float* __restrict__ b_ih,
                                               const float* __restrict__ b_hh,
                                               const float* __restrict__ ln_g,
                                               const float* __restrict__ ln_b,
                                               const float* __restrict__ bd1,
                                               const float* __restrict__ bd2,
                                               const float* __restrict__ Wd3,
                                               const float* __restrict__ bd3,
                                               const float* __restrict__ vacc,
                                               float* __restrict__ out) {
    __shared__ float scr_all[4][16 * 97];    // wave-private 16x97 stripes, 24.8 KB
    int wv = threadIdx.x >> 6, lane = threadIdx.x & 63;
    int tile = blockIdx.x * 4 + wv;
    if (tile >= Mm / 16) return;             // no barriers below -> safe early exit
    int m0 = tile * 16;
    float* scr = scr_all[wv];
    int lrow = lane & 15;                    // A/B operand row, D column
    int lhi = lane >> 4;                     // D row quad

    // vals passthrough (exact path)
    if (lane < 16) {
        float v = vacc[m0 + lane];
        out[Mm + m0 + lane] = fminf(fmaxf(v, -2.f), 3.5f);
    }

    // ---- fused msg reduction: 16 voxels, lane = dim; result -> LDS stripe --
    int myc = (lane < 16) ? cnt[m0 + lane] : 0;   // one coalesced cnt read
    for (int v = 0; v < 16; v++) {
        int c = __shfl(myc, v, 64);
        if (c > CAP) c = CAP;
        const int4* r4 = (const int4*)(rec + (size_t)(m0 + v) * CAP);
        float a0 = 0.f, a1 = 0.f, a2 = 0.f, a3 = 0.f;
        float w0 = 0.f, w1 = 0.f, w2 = 0.f, w3 = 0.f;
        for (int i0 = 0; i0 < c; i0 += 4) {
            int4 e = r4[i0 >> 2];            // wave-uniform record quad
            if (i0 + 0 < c) { float w = wbuf[e.x]; w0 += w; a0 = fmaf(w, f_pts[(size_t)(e.x >> 3) * Dd + lane], a0); }
            if (i0 + 1 < c) { float w = wbuf[e.y]; w1 += w; a1 = fmaf(w, f_pts[(size_t)(e.y >> 3) * Dd + lane], a1); }
            if (i0 + 2 < c) { float w = wbuf[e.z]; w2 += w; a2 = fmaf(w, f_pts[(size_t)(e.z >> 3) * Dd + lane], a2); }
            if (i0 + 3 < c) { float w = wbuf[e.w]; w3 += w; a3 = fmaf(w, f_pts[(size_t)(e.w >> 3) * Dd + lane], a3); }
        }
        float acc = (a0 + a1) + (a2 + a3);
        float wsum = (w0 + w1) + (w2 + w3);
        scr[v * 97 + lane] = acc / (wsum + 1e-6f);   // pre-normalized msg
    }
    __threadfence_block();

    // ---- A fragments: z from global, mg from the LDS stripe ----
    bf16x8 za[2], ma[2];
    const float* zrow = z_latent + (size_t)(m0 + lrow) * Dd + lhi * 8;
#pragma unroll
    for (int c = 0; c < 2; c++) {
        bf16x8 t0, t1;
#pragma unroll
        for (int j = 0; j < 8; j++) {
            t0[j] = f2bf(zrow[c * 32 + j]);
            t1[j] = f2bf(scr[lrow * 97 + c * 32 + lhi * 8 + j]);
        }
        za[c] = t0; ma[c] = t1;
    }
    const bf16x8* WF = (const bf16x8*)wsW;
#define BFRAG(off) (WF[(off) * 64 + lane])

    // ---- gate: relu([z,mg]@Wg1.T+bg1)@Wg2.T+bg2 -> sigmoid ----
    f32x4 g0 = {0.f, 0.f, 0.f, 0.f}, g1 = {0.f, 0.f, 0.f, 0.f};
    bf16x8 gateA[4] = {za[0], za[1], ma[0], ma[1]};
#pragma unroll
    for (int c = 0; c < 4; c++) {
        g0 = __builtin_amdgcn_mfma_f32_16x16x32_bf16(gateA[c], BFRAG(0 + c), g0, 0, 0, 0);
        g1 = __builtin_amdgcn_mfma_f32_16x16x32_bf16(gateA[c], BFRAG(4 + c), g1, 0, 0, 0);
    }
    float bgA = bg1[lrow], bgB = bg1[16 + lrow];
    float w2A = Wg2[lrow], w2B = Wg2[16 + lrow];
    float g[4];
#pragma unroll
    for (int r = 0; r < 4; r++) {
        float ga = fmaxf(g0[r] + bgA, 0.f) * w2A + fmaxf(g1[r] + bgB, 0.f) * w2B;
        ga += __shfl_xor(ga, 1, 64);
        ga += __shfl_xor(ga, 2, 64);
        ga += __shfl_xor(ga, 4, 64);
        ga += __shfl_xor(ga, 8, 64);
        g[r] = sigmoidf_(ga + bg2[0]);
    }

    // ---- GRU: 12 col-tiles of 16 outs (r:0-3, z:4-7, n:8-11) ----
    float zn[4][4];                          // [t][r] z_new in C-layout
    float ps[4] = {0.f, 0.f, 0.f, 0.f}, pq[4] = {0.f, 0.f, 0.f, 0.f};
#pragma unroll
    for (int t = 0; t < 4; t++) {
        f32x4 Ar = {0.f, 0.f, 0.f, 0.f}, Az = Ar, An = Ar, Br = Ar, Bz = Ar, Bn = Ar;
#pragma unroll
        for (int c = 0; c < 2; c++) {
            Ar = __builtin_amdgcn_mfma_f32_16x16x32_bf16(ma[c], BFRAG(8 + t * 2 + c), Ar, 0, 0, 0);
            Az = __builtin_amdgcn_mfma_f32_16x16x32_bf16(ma[c], BFRAG(8 + (t + 4) * 2 + c), Az, 0, 0, 0);
            An = __builtin_amdgcn_mfma_f32_16x16x32_bf16(ma[c], BFRAG(8 + (t + 8) * 2 + c), An, 0, 0, 0);
            Br = __builtin_amdgcn_mfma_f32_16x16x32_bf16(za[c], BFRAG(32 + t * 2 + c), Br, 0, 0, 0);
            Bz = __builtin_amdgcn_mfma_f32_16x16x32_bf16(za[c], BFRAG(32 + (t + 4) * 2 + c), Bz, 0, 0, 0);
            Bn = __builtin_amdgcn_mfma_f32_16x16x32_bf16(za[c], BFRAG(32 + (t + 8) * 2 + c), Bn, 0, 0, 0);
        }
        int oc = t * 16 + lrow;
        float bir = b_ih[oc], biz = b_ih[64 + oc], bin = b_ih[128 + oc];
        float bhr = b_hh[oc], bhz = b_hh[64 + oc], bhn = b_hh[128 + oc];
#pragma unroll
        for (int r = 0; r < 4; r++) {
            int row = lhi * 4 + r;
            float zo = z_latent[(size_t)(m0 + row) * Dd + oc];
            float rr = sigmoidf_(Ar[r] + bir + Br[r] + bhr);
            float uu = sigmoidf_(Az[r] + biz + Bz[r] + bhz);
            float nnv = tanh_fast(An[r] + bin + rr * (Bn[r] + bhn));
            float hn = (1.f - uu) * nnv + uu * zo;
            float z2 = zo + g[r] * (hn - zo);
            zn[t][r] = z2;
            ps[r] += z2;
            pq[r] = fmaf(z2, z2, pq[r]);
        }
    }
    // LN stats: reduce over 64 cols
    float mu[4], rs[4];
#pragma unroll
    for (int r = 0; r < 4; r++) {
        float s = ps[r], q = pq[r];
        s += __shfl_xor(s, 1, 64); q += __shfl_xor(q, 1, 64);
        s += __shfl_xor(s, 2, 64); q += __shfl_xor(q, 2, 64);
        s += __shfl_xor(s, 4, 64); q += __shfl_xor(q, 4, 64);
        s += __shfl_xor(s, 8, 64); q += __shfl_xor(q, 8, 64);
        float m = s * (1.f / 64.f);
        float v = q * (1.f / 64.f) - m * m;
        mu[r] = m;
        rs[r] = rsqrtf(v + 1e-5f);
    }
    // x = LN(z_new)  -> LDS (C-layout write, stride 97 = conflict-free)
#pragma unroll
    for (int t = 0; t < 4; t++) {
        int o = t * 16 + lrow;
        float lg = ln_g[o], lb = ln_b[o];
#pragma unroll
        for (int r = 0; r < 4; r++)
            scr[(lhi * 4 + r) * 97 + o] = (zn[t][r] - mu[r]) * rs[r] * lg + lb;
    }
    __threadfence_block();                   // cross-lane LDS visibility in-wave

    // x -> A-frags for fc1
    bf16x8 xa[2];
#pragma unroll
    for (int c = 0; c < 2; c++) {
        bf16x8 tb;
#pragma unroll
        for (int j = 0; j < 8; j++) tb[j] = f2bf(scr[lrow * 97 + c * 32 + lhi * 8 + j]);
        xa[c] = tb;
    }
    // fc1: 6 tiles x 2 chunks
    f32x4 h1t[6];
#pragma unroll
    for (int t = 0; t < 6; t++) h1t[t] = (f32x4){0.f, 0.f, 0.f, 0.f};
#pragma unroll
    for (int t = 0; t < 6; t++)
#pragma unroll
        for (int c = 0; c < 2; c++)
            h1t[t] = __builtin_amdgcn_mfma_f32_16x16x32_bf16(xa[c], BFRAG(56 + t * 2 + c), h1t[t], 0, 0, 0);
    float h1r[6][4];
#pragma unroll
    for (int t = 0; t < 6; t++) {
        float bb = bd1[t * 16 + lrow];
#pragma unroll
        for (int r = 0; r < 4; r++) {
            h1r[t][r] = fmaxf(h1t[t][r] + bb, 0.f);
            scr[(lhi * 4 + r) * 97 + t * 16 + lrow] = h1r[t][r];   // h1 -> LDS
        }
    }
    __threadfence_block();

    // h1 -> A-frags for fc2 (K=96, 3 chunks)
    bf16x8 ha[3];
#pragma unroll
    for (int c = 0; c < 3; c++) {
        bf16x8 tb;
#pragma unroll
        for (int j = 0; j < 8; j++) tb[j] = f2bf(scr[lrow * 97 + c * 32 + lhi * 8 + j]);
        ha[c] = tb;
    }
    // fc2 + residual + fc3
    f32x4 o2[6];
#pragma unroll
    for (int t = 0; t < 6; t++) o2[t] = (f32x4){0.f, 0.f, 0.f, 0.f};
#pragma unroll
    for (int t = 0; t < 6; t++)
#pragma unroll
        for (int c = 0; c < 3; c++)
            o2[t] = __builtin_amdgcn_mfma_f32_16x16x32_bf16(ha[c], BFRAG(68 + t * 3 + c), o2[t], 0, 0, 0);
    float pacc[4] = {0.f, 0.f, 0.f, 0.f};
#pragma unroll
    for (int t = 0; t < 6; t++) {
        int o = t * 16 + lrow;
        float bb = bd2[o], w3 = Wd3[o];
#pragma unroll
        for (int r = 0; r < 4; r++) {
            float hd2 = h1r[t][r] + fmaxf(o2[t][r] + bb, 0.f);
            pacc[r] = fmaf(hd2, w3, pacc[r]);
        }
    }
#pragma unroll
    for (int r = 0; r < 4; r++) {
        float s = pacc[r];
        s += __shfl_xor(s, 1, 64);
        s += __shfl_xor(s, 2, 64);
        s += __shfl_xor(s, 4, 64);
        s += __shfl_xor(s, 8, 64);
        if (lrow == 0) out[m0 + lhi * 4 + r] = sigmoidf_(s + bd3[0]);
    }
#undef BFRAG
}

extern "C" void kernel_launch(void* const* d_in, const int* in_sizes, int n_in,
                              void* d_out, int out_size, void* d_ws, size_t ws_size,
                              hipStream_t stream) {
    const float* pts      = (const float*)d_in[0];
    const float* f_pts    = (const float*)d_in[1];
    const float* z_lat    = (const float*)d_in[2];
    const float* vals     = (const float*)d_in[3];
    const float* centers  = (const float*)d_in[4];
    const float* Wf       = (const float*)d_in[5];
    const float* Wz       = (const float*)d_in[6];
    const float* w_delta  = (const float*)d_in[7];
    const float* b_delta  = (const float*)d_in[8];
    const float* log_temp = (const float*)d_in[9];
    const float* W_ih     = (const float*)d_in[10];
    const float* W_hh     = (const float*)d_in[11];
    const float* b_ih     = (const float*)d_in[12];
    const float* b_hh     = (const float*)d_in[13];
    const float* Wg1      = (const float*)d_in[14];
    const float* bg1      = (const float*)d_in[15];
    const float* Wg2      = (const float*)d_in[16];
    const float* bg2      = (const float*)d_in[17];
    const float* ln_g     = (const float*)d_in[18];
    const float* ln_b     = (const float*)d_in[19];
    const float* Wd1      = (const float*)d_in[20];
    const float* bd1      = (const float*)d_in[21];
    const float* Wd2      = (const float*)d_in[22];
    const float* bd2      = (const float*)d_in[23];
    const float* Wd3      = (const float*)d_in[24];
    const float* bd3      = (const float*)d_in[25];
    const int*   keys     = (const int*)d_in[26];
    const int*   cand     = (const int*)d_in[27];
    float* out = (float*)d_out;

    float* ws   = (float*)d_ws;
    float* Zall = ws;                            // M*16 f32; dead after k1 -> wsW aliases
    float* wbuf = Zall + (size_t)Mm * Pp;        // N*8
    float* vacc = wbuf + (size_t)Nn * Kk;        // M
    int*   cnt  = (int*)(vacc + Mm);             // M
    int*   rec  = cnt + Mm;                      // M*CAP
    float* cdot = (float*)(rec + (size_t)Mm * CAP);  // M
    int*   lut  = (int*)(cdot + Mm);             // 4097  (total ~30.7 MB)
    short* wsW  = (short*)Zall;                  // 86 frags * 64 lanes * 16 B = 88 KB

    hipMemsetAsync(cnt, 0, sizeof(int) * Mm, stream);
    hipMemcpyAsync(vacc, vals, sizeof(float) * Mm, hipMemcpyDeviceToDevice, stream);

    k0_projz<<<(Mm + 255) / 256, 256, 0, stream>>>(z_lat, Wz, centers, w_delta, keys,
                                                   Zall, cdot, lut);
    k1_route<<<Nn / 64, 256, 0, stream>>>(pts, f_pts, Wf, w_delta, b_delta, log_temp,
                                          keys, cand, Zall, cdot, lut, wbuf, vacc,
                                          cnt, rec);
    // pack AFTER k1: wsW aliases Zall
    k_pack<<<(86 * 64 + 255) / 256, 256, 0, stream>>>(Wg1, W_ih, W_hh, Wd1, Wd2, wsW);
    k3_mfma<<<(Mm / 16 + 3) / 4, 256, 0, stream>>>(z_lat, f_pts, wbuf, cnt, rec, wsW,
                                                   bg1, Wg2, bg2, b_ih, b_hh, ln_g,
                                                   ln_b, bd1, bd2, Wd3, bd3, vacc, out);
}

// Round 6
// 378.341 us; speedup vs baseline: 1.3210x; 1.3210x over previous
//
#include <hip/hip_runtime.h>
#include <math.h>

#define Nn 120000
#define Kk 8
#define Dd 64
#define Mm 100000
#define Pp 16
#define HGg 32
#define HDd 96
#define CAP 48   // per-voxel bucket capacity; Poisson(9.6) max ~31, P(>=48)~1e-23
#define LUTB 12  // prefix bits for 2-level search (keys < 2^30)

typedef __attribute__((ext_vector_type(8))) short bf16x8;
typedef __attribute__((ext_vector_type(4))) float f32x4;

__device__ __forceinline__ float sigmoidf_(float x) { return 1.f / (1.f + __expf(-x)); }
__device__ __forceinline__ float tanh_fast(float x) {
    float e = __expf(2.f * x);          // inf for big x -> 1; 0 for very neg -> -1
    return 1.f - 2.f / (e + 1.f);
}
// f32 -> bf16 round-to-nearest-even
__device__ __forceinline__ short f2bf(float f) {
    unsigned u = __float_as_uint(f);
    unsigned r = (u + 0x7fffu + ((u >> 16) & 1u)) >> 16;
    return (short)r;
}

// -- K0: 4 lanes/voxel. Zall = normalize(z@Wz.T); cdot; search LUT ----------
__global__ __launch_bounds__(256) void k0_projz(const float* __restrict__ z,
                                                const float* __restrict__ Wz,
                                                const float* __restrict__ centers,
                                                const float* __restrict__ w_delta,
                                                const int* __restrict__ keys,
                                                float* __restrict__ Zall,
                                                float* __restrict__ cdot,
                                                int* __restrict__ lut) {
    int g = threadIdx.x & 3;
    int m = blockIdx.x * 64 + (threadIdx.x >> 2);
    if (m >= Mm) return;
    // 2-level search LUT: lut[p] = lower_bound(keys, p << (30-LUTB))
    if (g == 0 && m <= (1 << LUTB)) {
        int target = m << (30 - LUTB);
        int lo = 0, hi = Mm;
        while (lo < hi) {
            int mid = (lo + hi) >> 1;
            if (keys[mid] < target) lo = mid + 1; else hi = mid;
        }
        lut[m] = lo;
    }
    // partial dots over this lane's 16-dim quarter
    const float4* zr = (const float4*)(z + (size_t)m * Dd + g * 16);
    float4 q0 = zr[0], q1 = zr[1], q2 = zr[2], q3 = zr[3];
    float acc[Pp];
#pragma unroll
    for (int p = 0; p < Pp; p++) {
        const float4* w = (const float4*)(Wz + (size_t)p * Dd + g * 16);
        float4 w0 = w[0], w1 = w[1], w2 = w[2], w3 = w[3];
        float s = q0.x * w0.x + q0.y * w0.y + q0.z * w0.z + q0.w * w0.w;
        s += q1.x * w1.x + q1.y * w1.y + q1.z * w1.z + q1.w * w1.w;
        s += q2.x * w2.x + q2.y * w2.y + q2.z * w2.z + q2.w * w2.w;
        s += q3.x * w3.x + q3.y * w3.y + q3.z * w3.z + q3.w * w3.w;
        acc[p] = s;
    }
#pragma unroll
    for (int p = 0; p < Pp; p++) {
        acc[p] += __shfl_xor(acc[p], 1, 64);
        acc[p] += __shfl_xor(acc[p], 2, 64);
    }
    float ss = 0.f;
#pragma unroll
    for (int p = 0; p < Pp; p++) ss = fmaf(acc[p], acc[p], ss);
    float inv = 1.f / (sqrtf(ss) + 1e-6f);
    // lane g stores elements {i*4+g}: per-instruction addresses coalesce
#pragma unroll
    for (int i = 0; i < 4; i++) {
        float v = (g == 0) ? acc[i * 4] : (g == 1) ? acc[i * 4 + 1]
                : (g == 2) ? acc[i * 4 + 2] : acc[i * 4 + 3];
        Zall[(size_t)m * Pp + i * 4 + g] = v * inv;
    }
    if (g == 0)
        cdot[m] = centers[3 * m] * w_delta[0] + centers[3 * m + 1] * w_delta[1]
                + centers[3 * m + 2] * w_delta[2];
}

// --- K1: 4 lanes per point. hash + LUT search + vacc atomic; Fp group dots;
//         2 candidates/lane; group softmax; bucket insert (nt stores) -------
__global__ __launch_bounds__(256) void k1_route(const float* __restrict__ pts,
                                                const float* __restrict__ f_pts,
                                                const float* __restrict__ Wf,
                                                const float* __restrict__ w_delta,
                                                const float* __restrict__ b_delta,
                                                const float* __restrict__ log_temp,
                                                const int* __restrict__ keys,
                                                const int* __restrict__ cand,
                                                const float* __restrict__ Zall,
                                                const float* __restrict__ cdot,
                                                const int* __restrict__ lut,
                                                float* __restrict__ wbuf,
                                                float* __restrict__ vacc,
                                                int* __restrict__ cnt,
                                                int* __restrict__ rec) {
    int g = threadIdx.x & 3;                         // lane-in-group
    int n = blockIdx.x * 64 + (threadIdx.x >> 2);    // grid = 1875 exact

    float px = pts[3 * n], py = pts[3 * n + 1], pz = pts[3 * n + 2];

    // candidate ids early (ILP): lane handles k = 2g, 2g+1
    int2 myid = ((const int2*)(cand + (size_t)n * Kk))[g];

    // IEEE f32 divide then floor, matching the reference exactly
    int ix = (int)floorf(px / 0.1f);
    int iy = (int)floorf(py / 0.1f);
    int iz = (int)floorf(pz / 0.1f);
    int h = ((ix + 512) << 20) ^ ((iy + 512) << 10) ^ (iz + 512);
    // lower_bound via prefix LUT (h in [0,2^30)): ~24-key segment -> ~5 hops
    int pfx = h >> (30 - LUTB);
    int lo = lut[pfx], hi = lut[pfx + 1];
    while (lo < hi) {
        int mid = (lo + hi) >> 1;
        if (keys[mid] < h) lo = mid + 1; else hi = mid;
    }
    int vi = lo < (Mm - 1) ? lo : (Mm - 1);
    if (g == 0) atomicAdd(vacc + vi, 0.5f);

    // ---- Fp partial dots over this lane's 16-float quarter ----
    const float4* fr = (const float4*)(f_pts + (size_t)n * Dd + g * 16);
    float4 q0 = fr[0], q1 = fr[1], q2 = fr[2], q3 = fr[3];
    float fp[Pp];
#pragma unroll
    for (int p = 0; p < Pp; p++) {
        const float4* w = (const float4*)(Wf + (size_t)p * Dd + g * 16);
        float4 w0 = w[0], w1 = w[1], w2 = w[2], w3 = w[3];
        float s = q0.x * w0.x + q0.y * w0.y + q0.z * w0.z + q0.w * w0.w;
        s += q1.x * w1.x + q1.y * w1.y + q1.z * w1.z + q1.w * w1.w;
        s += q2.x * w2.x + q2.y * w2.y + q2.z * w2.z + q2.w * w2.w;
        s += q3.x * w3.x + q3.y * w3.y + q3.z * w3.z + q3.w * w3.w;
        fp[p] = s;
    }
#pragma unroll
    for (int p = 0; p < Pp; p++) {
        fp[p] += __shfl_xor(fp[p], 1, 64);
        fp[p] += __shfl_xor(fp[p], 2, 64);
    }
    float ss = 0.f;
#pragma unroll
    for (int p = 0; p < Pp; p++) ss = fmaf(fp[p], fp[p], ss);
    float inv = 1.f / (sqrtf(ss) + 1e-6f);
#pragma unroll
    for (int p = 0; p < Pp; p++) fp[p] *= inv;

    float et = expf(log_temp[0]);
    float pdot = px * w_delta[0] + py * w_delta[1] + pz * w_delta[2] + b_delta[0];

    int ids[2] = {myid.x, myid.y};
    float sims[2];
#pragma unroll
    for (int t = 0; t < 2; t++) {
        int id = ids[t];
        const float4* zp = (const float4*)(Zall + (size_t)id * Pp);
        float4 z0 = zp[0], z1 = zp[1], z2 = zp[2], z3 = zp[3];
        float core = fp[0] * z0.x + fp[1] * z0.y + fp[2] * z0.z + fp[3] * z0.w;
        core += fp[4] * z1.x + fp[5] * z1.y + fp[6] * z1.z + fp[7] * z1.w;
        core += fp[8] * z2.x + fp[9] * z2.y + fp[10] * z2.z + fp[11] * z2.w;
        core += fp[12] * z3.x + fp[13] * z3.y + fp[14] * z3.z + fp[15] * z3.w;
        float dt = pdot - cdot[id];
        sims[t] = et * (core + dt) / 0.3f;
    }
    float mx = fmaxf(sims[0], sims[1]);
    mx = fmaxf(mx, __shfl_xor(mx, 1, 64));
    mx = fmaxf(mx, __shfl_xor(mx, 2, 64));
    float e0 = __expf(sims[0] - mx), e1 = __expf(sims[1] - mx);
    float se = e0 + e1;
    se += __shfl_xor(se, 1, 64);
    se += __shfl_xor(se, 2, 64);
    float isum = 1.f / se;
    float w0 = e0 * isum, w1 = e1 * isum;
    ((float2*)(wbuf + (size_t)n * Kk))[g] = make_float2(w0, w1);

    int p0 = atomicAdd(cnt + ids[0], 1);
    if (p0 < CAP)
        __builtin_nontemporal_store((n << 3) | (2 * g), rec + (size_t)ids[0] * CAP + p0);
    int p1 = atomicAdd(cnt + ids[1], 1);
    if (p1 < CAP)
        __builtin_nontemporal_store((n << 3) | (2 * g + 1), rec + (size_t)ids[1] * CAP + p1);
}

// ---- K2: gather-reduce per voxel (wave/voxel, lane=dim); fused wsum norm ---
__global__ __launch_bounds__(256) void k2_reduce(const float* __restrict__ f_pts,
                                                 const float* __restrict__ wbuf,
                                                 const int* __restrict__ cnt,
                                                 const int* __restrict__ rec,
                                                 float* __restrict__ msg) {
    int wv = threadIdx.x >> 6, lane = threadIdx.x & 63;
    int m = blockIdx.x * 4 + wv;
    if (m >= Mm) return;
    int c = cnt[m];
    if (c > CAP) c = CAP;
    const int4* r4 = (const int4*)(rec + (size_t)m * CAP);
    float a0 = 0.f, a1 = 0.f, a2 = 0.f, a3 = 0.f;
    float w0 = 0.f, w1 = 0.f, w2 = 0.f, w3 = 0.f;
    for (int i0 = 0; i0 < c; i0 += 4) {
        int4 e = r4[i0 >> 2];              // wave-uniform record quad
        if (i0 + 0 < c) { float w = wbuf[e.x]; w0 += w; a0 = fmaf(w, f_pts[(size_t)(e.x >> 3) * Dd + lane], a0); }
        if (i0 + 1 < c) { float w = wbuf[e.y]; w1 += w; a1 = fmaf(w, f_pts[(size_t)(e.y >> 3) * Dd + lane], a1); }
        if (i0 + 2 < c) { float w = wbuf[e.z]; w2 += w; a2 = fmaf(w, f_pts[(size_t)(e.z >> 3) * Dd + lane], a2); }
        if (i0 + 3 < c) { float w = wbuf[e.w]; w3 += w; a3 = fmaf(w, f_pts[(size_t)(e.w >> 3) * Dd + lane], a3); }
    }
    float acc = (a0 + a1) + (a2 + a3);
    float wsum = (w0 + w1) + (w2 + w3);
    msg[(size_t)m * Dd + lane] = acc / (wsum + 1e-6f);   // pre-normalized msg
}

// ---------------- K_pack: weights -> bf16 MFMA B-fragment layout ------------
// frag f, lane l: 8 bf16 = W[o = t*16 + (l&15)][k = c*32 + (l>>4)*8 + j]
__global__ __launch_bounds__(256) void k_pack(const float* __restrict__ Wg1,
                                              const float* __restrict__ W_ih,
                                              const float* __restrict__ W_hh,
                                              const float* __restrict__ Wd1,
                                              const float* __restrict__ Wd2,
                                              short* __restrict__ wsW) {
    int idx = blockIdx.x * 256 + threadIdx.x;
    if (idx >= 86 * 64) return;
    int f = idx >> 6, lane = idx & 63;
    int lrow = lane & 15, lhi = lane >> 4;
    const float* src;
    int t, c, K;
    if (f < 8)       { int g = f;      t = g >> 2; c = g & 3;  src = Wg1;  K = 128; }
    else if (f < 32) { int g = f - 8;  t = g >> 1; c = g & 1;  src = W_ih; K = 64; }
    else if (f < 56) { int g = f - 32; t = g >> 1; c = g & 1;  src = W_hh; K = 64; }
    else if (f < 68) { int g = f - 56; t = g >> 1; c = g & 1;  src = Wd1;  K = 64; }
    else             { int g = f - 68; t = g / 3;  c = g % 3;  src = Wd2;  K = 96; }
    int o = t * 16 + lrow;
    int k0 = c * 32 + lhi * 8;
    short* dst = wsW + ((size_t)f * 64 + lane) * 8;
#pragma unroll
    for (int j = 0; j < 8; j++) dst[j] = f2bf(src[(size_t)o * K + k0 + j]);
}

// ---- K3: MFMA voxel pipeline, wave/16 voxels; phase-grouped B-frag loads ---
// __launch_bounds__(256,3): ~170 VGPR cap so grouped fragment loads stay in
// flight instead of serializing on vmcnt (r4's 68-VGPR alloc stalled ~80k cyc).
__global__ __launch_bounds__(256, 3) void k3_mfma(const float* __restrict__ z_latent,
                                                  const float* __restrict__ msg,
                                                  const short* __restrict__ wsW,
                                                  const float* __restrict__ bg1,
                                                  const float* __restrict__ Wg2,
                                                  const float* __restrict__ bg2,
                                                  const float* __restrict__ b_ih,
                                                  const float* __restrict__ b_hh,
                                                  const float* __restrict__ ln_g,
                                                  const float* __restrict__ ln_b,
                                                  const float* __restrict__ bd1,
                                                  const float* __restrict__ bd2,
                                                  const float* __restrict__ Wd3,
                                                  const float* __restrict__ bd3,
                                                  const float* __restrict__ vacc,
                                                  float* __restrict__ out) {
    __shared__ float scr_all[4][16 * 97];    // wave-private 16x97 stripes, 24.8 KB
    int wv = threadIdx.x >> 6, lane = threadIdx.x & 63;
    int tile = blockIdx.x * 4 + wv;
    if (tile >= Mm / 16) return;             // no barriers below -> safe early exit
    int m0 = tile * 16;
    float* scr = scr_all[wv];
    int lrow = lane & 15;                    // A/B operand row, D column
    int lhi = lane >> 4;                     // D row quad

    // vals passthrough (exact path)
    if (lane < 16) {
        float v = vacc[m0 + lane];
        out[Mm + m0 + lane] = fminf(fmaxf(v, -2.f), 3.5f);
    }

    const bf16x8* WF = (const bf16x8*)wsW;
#define BFRAG(off) (WF[(off) * 64 + lane])

    // ---- A fragments: z, mg (16 rows x 64 K, 2 k-chunks each) ----
    bf16x8 za[2], ma[2];
    const float* zrow = z_latent + (size_t)(m0 + lrow) * Dd + lhi * 8;
    const float* mrow = msg + (size_t)(m0 + lrow) * Dd + lhi * 8;   // pre-normalized
#pragma unroll
    for (int c = 0; c < 2; c++) {
        bf16x8 t0, t1;
#pragma unroll
        for (int j = 0; j < 8; j++) {
            t0[j] = f2bf(zrow[c * 32 + j]);
            t1[j] = f2bf(mrow[c * 32 + j]);
        }
        za[c] = t0; ma[c] = t1;
    }

    // ---- gate: grouped 8-frag load, then 8 MFMAs ----
    bf16x8 wgf[8];
#pragma unroll
    for (int j = 0; j < 8; j++) wgf[j] = BFRAG(j);
    f32x4 g0 = {0.f, 0.f, 0.f, 0.f}, g1 = {0.f, 0.f, 0.f, 0.f};
    bf16x8 gateA[4] = {za[0], za[1], ma[0], ma[1]};
#pragma unroll
    for (int c = 0; c < 4; c++) {
        g0 = __builtin_amdgcn_mfma_f32_16x16x32_bf16(gateA[c], wgf[c], g0, 0, 0, 0);
        g1 = __builtin_amdgcn_mfma_f32_16x16x32_bf16(gateA[c], wgf[4 + c], g1, 0, 0, 0);
    }
    float bgA = bg1[lrow], bgB = bg1[16 + lrow];
    float w2A = Wg2[lrow], w2B = Wg2[16 + lrow];
    float g[4];
#pragma unroll
    for (int r = 0; r < 4; r++) {
        float ga = fmaxf(g0[r] + bgA, 0.f) * w2A + fmaxf(g1[r] + bgB, 0.f) * w2B;
        ga += __shfl_xor(ga, 1, 64);
        ga += __shfl_xor(ga, 2, 64);
        ga += __shfl_xor(ga, 4, 64);
        ga += __shfl_xor(ga, 8, 64);
        g[r] = sigmoidf_(ga + bg2[0]);
    }

    // ---- GRU: 4 col-tiles; per-tile grouped 12-frag load, then 12 MFMAs ----
    float zn[4][4];                          // [t][r] z_new in C-layout
    float ps[4] = {0.f, 0.f, 0.f, 0.f}, pq[4] = {0.f, 0.f, 0.f, 0.f};
#pragma unroll
    for (int t = 0; t < 4; t++) {
        bf16x8 wt[12];
#pragma unroll
        for (int c = 0; c < 2; c++) {
            wt[0 + c]  = BFRAG(8 + t * 2 + c);            // ih r
            wt[2 + c]  = BFRAG(8 + (t + 4) * 2 + c);      // ih z
            wt[4 + c]  = BFRAG(8 + (t + 8) * 2 + c);      // ih n
            wt[6 + c]  = BFRAG(32 + t * 2 + c);           // hh r
            wt[8 + c]  = BFRAG(32 + (t + 4) * 2 + c);     // hh z
            wt[10 + c] = BFRAG(32 + (t + 8) * 2 + c);     // hh n
        }
        f32x4 Ar = {0.f, 0.f, 0.f, 0.f}, Az = Ar, An = Ar, Br = Ar, Bz = Ar, Bn = Ar;
#pragma unroll
        for (int c = 0; c < 2; c++) {
            Ar = __builtin_amdgcn_mfma_f32_16x16x32_bf16(ma[c], wt[0 + c], Ar, 0, 0, 0);
            Az = __builtin_amdgcn_mfma_f32_16x16x32_bf16(ma[c], wt[2 + c], Az, 0, 0, 0);
            An = __builtin_amdgcn_mfma_f32_16x16x32_bf16(ma[c], wt[4 + c], An, 0, 0, 0);
            Br = __builtin_amdgcn_mfma_f32_16x16x32_bf16(za[c], wt[6 + c], Br, 0, 0, 0);
            Bz = __builtin_amdgcn_mfma_f32_16x16x32_bf16(za[c], wt[8 + c], Bz, 0, 0, 0);
            Bn = __builtin_amdgcn_mfma_f32_16x16x32_bf16(za[c], wt[10 + c], Bn, 0, 0, 0);
        }
        int oc = t * 16 + lrow;
        float bir = b_ih[oc], biz = b_ih[64 + oc], bin = b_ih[128 + oc];
        float bhr = b_hh[oc], bhz = b_hh[64 + oc], bhn = b_hh[128 + oc];
#pragma unroll
        for (int r = 0; r < 4; r++) {
            int row = lhi * 4 + r;
            float zo = z_latent[(size_t)(m0 + row) * Dd + oc];
            float rr = sigmoidf_(Ar[r] + bir + Br[r] + bhr);
            float uu = sigmoidf_(Az[r] + biz + Bz[r] + bhz);
            float nnv = tanh_fast(An[r] + bin + rr * (Bn[r] + bhn));
            float hn = (1.f - uu) * nnv + uu * zo;
            float z2 = zo + g[r] * (hn - zo);
            zn[t][r] = z2;
            ps[r] += z2;
            pq[r] = fmaf(z2, z2, pq[r]);
        }
    }
    // LN stats: reduce over 64 cols
    float mu[4], rs[4];
#pragma unroll
    for (int r = 0; r < 4; r++) {
        float s = ps[r], q = pq[r];
        s += __shfl_xor(s, 1, 64); q += __shfl_xor(q, 1, 64);
        s += __shfl_xor(s, 2, 64); q += __shfl_xor(q, 2, 64);
        s += __shfl_xor(s, 4, 64); q += __shfl_xor(q, 4, 64);
        s += __shfl_xor(s, 8, 64); q += __shfl_xor(q, 8, 64);
        float m = s * (1.f / 64.f);
        float v = q * (1.f / 64.f) - m * m;
        mu[r] = m;
        rs[r] = rsqrtf(v + 1e-5f);
    }
    // x = LN(z_new)  -> LDS (C-layout write, stride 97 = conflict-free)
#pragma unroll
    for (int t = 0; t < 4; t++) {
        int o = t * 16 + lrow;
        float lg = ln_g[o], lb = ln_b[o];
#pragma unroll
        for (int r = 0; r < 4; r++)
            scr[(lhi * 4 + r) * 97 + o] = (zn[t][r] - mu[r]) * rs[r] * lg + lb;
    }
    __threadfence_block();                   // cross-lane LDS visibility in-wave

    // x -> A-frags for fc1
    bf16x8 xa[2];
#pragma unroll
    for (int c = 0; c < 2; c++) {
        bf16x8 tb;
#pragma unroll
        for (int j = 0; j < 8; j++) tb[j] = f2bf(scr[lrow * 97 + c * 32 + lhi * 8 + j]);
        xa[c] = tb;
    }
    // fc1: grouped 12-frag load, then 12 MFMAs
    bf16x8 wf1[12];
#pragma unroll
    for (int j = 0; j < 12; j++) wf1[j] = BFRAG(56 + j);
    f32x4 h1t[6];
#pragma unroll
    for (int t = 0; t < 6; t++) h1t[t] = (f32x4){0.f, 0.f, 0.f, 0.f};
#pragma unroll
    for (int t = 0; t < 6; t++)
#pragma unroll
        for (int c = 0; c < 2; c++)
            h1t[t] = __builtin_amdgcn_mfma_f32_16x16x32_bf16(xa[c], wf1[t * 2 + c], h1t[t], 0, 0, 0);
    float h1r[6][4];
#pragma unroll
    for (int t = 0; t < 6; t++) {
        float bb = bd1[t * 16 + lrow];
#pragma unroll
        for (int r = 0; r < 4; r++) {
            h1r[t][r] = fmaxf(h1t[t][r] + bb, 0.f);
            scr[(lhi * 4 + r) * 97 + t * 16 + lrow] = h1r[t][r];   // h1 -> LDS
        }
    }
    __threadfence_block();

    // h1 -> A-frags for fc2 (K=96, 3 chunks)
    bf16x8 ha[3];
#pragma unroll
    for (int c = 0; c < 3; c++) {
        bf16x8 tb;
#pragma unroll
        for (int j = 0; j < 8; j++) tb[j] = f2bf(scr[lrow * 97 + c * 32 + lhi * 8 + j]);
        ha[c] = tb;
    }
    // fc2: grouped 18-frag load, then 18 MFMAs; + residual + fc3
    bf16x8 wf2[18];
#pragma unroll
    for (int j = 0; j < 18; j++) wf2[j] = BFRAG(68 + j);
    f32x4 o2[6];
#pragma unroll
    for (int t = 0; t < 6; t++) o2[t] = (f32x4){0.f, 0.f, 0.f, 0.f};
#pragma unroll
    for (int t = 0; t < 6; t++)
#pragma unroll
        for (int c = 0; c < 3; c++)
            o2[t] = __builtin_amdgcn_mfma_f32_16x16x32_bf16(ha[c], wf2[t * 3 + c], o2[t], 0, 0, 0);
    float pacc[4] = {0.f, 0.f, 0.f, 0.f};
#pragma unroll
    for (int t = 0; t < 6; t++) {
        int o = t * 16 + lrow;
        float bb = bd2[o], w3 = Wd3[o];
#pragma unroll
        for (int r = 0; r < 4; r++) {
            float hd2 = h1r[t][r] + fmaxf(o2[t][r] + bb, 0.f);
            pacc[r] = fmaf(hd2, w3, pacc[r]);
        }
    }
#pragma unroll
    for (int r = 0; r < 4; r++) {
        float s = pacc[r];
        s += __shfl_xor(s, 1, 64);
        s += __shfl_xor(s, 2, 64);
        s += __shfl_xor(s, 4, 64);
        s += __shfl_xor(s, 8, 64);
        if (lrow == 0) out[m0 + lhi * 4 + r] = sigmoidf_(s + bd3[0]);
    }
#undef BFRAG
}

extern "C" void kernel_launch(void* const* d_in, const int* in_sizes, int n_in,
                              void* d_out, int out_size, void* d_ws, size_t ws_size,
                              hipStream_t stream) {
    const float* pts      = (const float*)d_in[0];
    const float* f_pts    = (const float*)d_in[1];
    const float* z_lat    = (const float*)d_in[2];
    const float* vals     = (const float*)d_in[3];
    const float* centers  = (const float*)d_in[4];
    const float* Wf       = (const float*)d_in[5];
    const float* Wz       = (const float*)d_in[6];
    const float* w_delta  = (const float*)d_in[7];
    const float* b_delta  = (const float*)d_in[8];
    const float* log_temp = (const float*)d_in[9];
    const float* W_ih     = (const float*)d_in[10];
    const float* W_hh     = (const float*)d_in[11];
    const float* b_ih     = (const float*)d_in[12];
    const float* b_hh     = (const float*)d_in[13];
    const float* Wg1      = (const float*)d_in[14];
    const float* bg1      = (const float*)d_in[15];
    const float* Wg2      = (const float*)d_in[16];
    const float* bg2      = (const float*)d_in[17];
    const float* ln_g     = (const float*)d_in[18];
    const float* ln_b     = (const float*)d_in[19];
    const float* Wd1      = (const float*)d_in[20];
    const float* bd1      = (const float*)d_in[21];
    const float* Wd2      = (const float*)d_in[22];
    const float* bd2      = (const float*)d_in[23];
    const float* Wd3      = (const float*)d_in[24];
    const float* bd3      = (const float*)d_in[25];
    const int*   keys     = (const int*)d_in[26];
    const int*   cand     = (const int*)d_in[27];
    float* out = (float*)d_out;

    float* ws   = (float*)d_ws;
    float* Zall = ws;                            // M*16 f32; dead after k1 -> wsW aliases
    float* wbuf = Zall + (size_t)Mm * Pp;        // N*8
    float* msg  = wbuf + (size_t)Nn * Kk;        // M*64 (written once by k2_reduce)
    float* vacc = msg + (size_t)Mm * Dd;         // M
    int*   cnt  = (int*)(vacc + Mm);             // M
    int*   rec  = cnt + Mm;                      // M*CAP
    float* cdot = (float*)(rec + (size_t)Mm * CAP);  // M
    int*   lut  = (int*)(cdot + Mm);             // 4097  (total ~56.3 MB)
    short* wsW  = (short*)Zall;                  // 86 frags * 64 lanes * 16 B = 88 KB

    hipMemsetAsync(cnt, 0, sizeof(int) * Mm, stream);
    hipMemcpyAsync(vacc, vals, sizeof(float) * Mm, hipMemcpyDeviceToDevice, stream);

    k0_projz<<<(Mm * 4 + 255) / 256, 256, 0, stream>>>(z_lat, Wz, centers, w_delta,
                                                       keys, Zall, cdot, lut);
    k1_route<<<Nn / 64, 256, 0, stream>>>(pts, f_pts, Wf, w_delta, b_delta, log_temp,
                                          keys, cand, Zall, cdot, lut, wbuf, vacc,
                                          cnt, rec);
    // pack AFTER k1: wsW aliases Zall
    k_pack<<<(86 * 64 + 255) / 256, 256, 0, stream>>>(Wg1, W_ih, W_hh, Wd1, Wd2, wsW);
    k2_reduce<<<(Mm + 3) / 4, 256, 0, stream>>>(f_pts, wbuf, cnt, rec, msg);
    k3_mfma<<<(Mm / 16 + 3) / 4, 256, 0, stream>>>(z_lat, msg, wsW, bg1, Wg2, bg2,
                                                   b_ih, b_hh, ln_g, ln_b, bd1, bd2,
                                                   Wd3, bd3, vacc, out);
}

// Round 7
// 374.285 us; speedup vs baseline: 1.3353x; 1.0108x over previous
//
#include <hip/hip_runtime.h>
#include <math.h>

#define Nn 120000
#define Kk 8
#define Dd 64
#define Mm 100000
#define Pp 16
#define HGg 32
#define HDd 96
#define CAP 40   // per-voxel bucket capacity; actual max ~27-31 (Poisson 9.6 over fixed seed)
#define LUTB 12  // prefix bits for 2-level search (keys < 2^30)

typedef __attribute__((ext_vector_type(8))) short bf16x8;
typedef __attribute__((ext_vector_type(4))) float f32x4;

__device__ __forceinline__ float sigmoidf_(float x) { return 1.f / (1.f + __expf(-x)); }
__device__ __forceinline__ float tanh_fast(float x) {
    float e = __expf(2.f * x);          // inf for big x -> 1; 0 for very neg -> -1
    return 1.f - 2.f / (e + 1.f);
}
// f32 -> bf16 round-to-nearest-even
__device__ __forceinline__ short f2bf(float f) {
    unsigned u = __float_as_uint(f);
    unsigned r = (u + 0x7fffu + ((u >> 16) & 1u)) >> 16;
    return (short)r;
}
__device__ __forceinline__ float bf2f(unsigned short u) {
    return __uint_as_float(((unsigned)u) << 16);
}

// -- K0: 4 lanes/voxel. Zall = normalize(z@Wz.T); cdot; search LUT ----------
__global__ __launch_bounds__(256) void k0_projz(const float* __restrict__ z,
                                                const float* __restrict__ Wz,
                                                const float* __restrict__ centers,
                                                const float* __restrict__ w_delta,
                                                const int* __restrict__ keys,
                                                float* __restrict__ Zall,
                                                float* __restrict__ cdot,
                                                int* __restrict__ lut) {
    int g = threadIdx.x & 3;
    int m = blockIdx.x * 64 + (threadIdx.x >> 2);
    if (m >= Mm) return;
    // 2-level search LUT: lut[p] = lower_bound(keys, p << (30-LUTB))
    if (g == 0 && m <= (1 << LUTB)) {
        int target = m << (30 - LUTB);
        int lo = 0, hi = Mm;
        while (lo < hi) {
            int mid = (lo + hi) >> 1;
            if (keys[mid] < target) lo = mid + 1; else hi = mid;
        }
        lut[m] = lo;
    }
    // partial dots over this lane's 16-dim quarter
    const float4* zr = (const float4*)(z + (size_t)m * Dd + g * 16);
    float4 q0 = zr[0], q1 = zr[1], q2 = zr[2], q3 = zr[3];
    float acc[Pp];
#pragma unroll
    for (int p = 0; p < Pp; p++) {
        const float4* w = (const float4*)(Wz + (size_t)p * Dd + g * 16);
        float4 w0 = w[0], w1 = w[1], w2 = w[2], w3 = w[3];
        float s = q0.x * w0.x + q0.y * w0.y + q0.z * w0.z + q0.w * w0.w;
        s += q1.x * w1.x + q1.y * w1.y + q1.z * w1.z + q1.w * w1.w;
        s += q2.x * w2.x + q2.y * w2.y + q2.z * w2.z + q2.w * w2.w;
        s += q3.x * w3.x + q3.y * w3.y + q3.z * w3.z + q3.w * w3.w;
        acc[p] = s;
    }
#pragma unroll
    for (int p = 0; p < Pp; p++) {
        acc[p] += __shfl_xor(acc[p], 1, 64);
        acc[p] += __shfl_xor(acc[p], 2, 64);
    }
    float ss = 0.f;
#pragma unroll
    for (int p = 0; p < Pp; p++) ss = fmaf(acc[p], acc[p], ss);
    float inv = 1.f / (sqrtf(ss) + 1e-6f);
    // lane g stores elements {i*4+g}: per-instruction addresses coalesce
#pragma unroll
    for (int i = 0; i < 4; i++) {
        float v = (g == 0) ? acc[i * 4] : (g == 1) ? acc[i * 4 + 1]
                : (g == 2) ? acc[i * 4 + 2] : acc[i * 4 + 3];
        Zall[(size_t)m * Pp + i * 4 + g] = v * inv;
    }
    if (g == 0)
        cdot[m] = centers[3 * m] * w_delta[0] + centers[3 * m + 1] * w_delta[1]
                + centers[3 * m + 2] * w_delta[2];
}

// --- K1: 4 lanes/point. search masked to g==0 (1/4 the keys gathers);
//         2 candidates/lane; group softmax; int2(n,w) nt bucket insert ------
__global__ __launch_bounds__(256) void k1_route(const float* __restrict__ pts,
                                                const float* __restrict__ f_pts,
                                                const float* __restrict__ Wf,
                                                const float* __restrict__ w_delta,
                                                const float* __restrict__ b_delta,
                                                const float* __restrict__ log_temp,
                                                const int* __restrict__ keys,
                                                const int* __restrict__ cand,
                                                const float* __restrict__ Zall,
                                                const float* __restrict__ cdot,
                                                const int* __restrict__ lut,
                                                float* __restrict__ vacc,
                                                int* __restrict__ cnt,
                                                int2* __restrict__ rec) {
    int g = threadIdx.x & 3;                         // lane-in-group
    int n = blockIdx.x * 64 + (threadIdx.x >> 2);    // grid = 1875 exact

    float px = pts[3 * n], py = pts[3 * n + 1], pz = pts[3 * n + 2];

    // candidate ids early (ILP): lane handles k = 2g, 2g+1
    int2 myid = ((const int2*)(cand + (size_t)n * Kk))[g];

    // hash + search only on lane 0 of each group (others would be redundant)
    if (g == 0) {
        // IEEE f32 divide then floor, matching the reference exactly
        int ix = (int)floorf(px / 0.1f);
        int iy = (int)floorf(py / 0.1f);
        int iz = (int)floorf(pz / 0.1f);
        int h = ((ix + 512) << 20) ^ ((iy + 512) << 10) ^ (iz + 512);
        int pfx = h >> (30 - LUTB);
        int lo = lut[pfx], hi = lut[pfx + 1];
        while (lo < hi) {
            int mid = (lo + hi) >> 1;
            if (keys[mid] < h) lo = mid + 1; else hi = mid;
        }
        int vi = lo < (Mm - 1) ? lo : (Mm - 1);
        atomicAdd(vacc + vi, 0.5f);
    }

    // ---- Fp partial dots over this lane's 16-float quarter ----
    const float4* fr = (const float4*)(f_pts + (size_t)n * Dd + g * 16);
    float4 q0 = fr[0], q1 = fr[1], q2 = fr[2], q3 = fr[3];
    float fp[Pp];
#pragma unroll
    for (int p = 0; p < Pp; p++) {
        const float4* w = (const float4*)(Wf + (size_t)p * Dd + g * 16);
        float4 w0 = w[0], w1 = w[1], w2 = w[2], w3 = w[3];
        float s = q0.x * w0.x + q0.y * w0.y + q0.z * w0.z + q0.w * w0.w;
        s += q1.x * w1.x + q1.y * w1.y + q1.z * w1.z + q1.w * w1.w;
        s += q2.x * w2.x + q2.y * w2.y + q2.z * w2.z + q2.w * w2.w;
        s += q3.x * w3.x + q3.y * w3.y + q3.z * w3.z + q3.w * w3.w;
        fp[p] = s;
    }
#pragma unroll
    for (int p = 0; p < Pp; p++) {
        fp[p] += __shfl_xor(fp[p], 1, 64);
        fp[p] += __shfl_xor(fp[p], 2, 64);
    }
    float ss = 0.f;
#pragma unroll
    for (int p = 0; p < Pp; p++) ss = fmaf(fp[p], fp[p], ss);
    float inv = 1.f / (sqrtf(ss) + 1e-6f);
#pragma unroll
    for (int p = 0; p < Pp; p++) fp[p] *= inv;

    float et = expf(log_temp[0]);
    float pdot = px * w_delta[0] + py * w_delta[1] + pz * w_delta[2] + b_delta[0];

    int ids[2] = {myid.x, myid.y};
    float sims[2];
#pragma unroll
    for (int t = 0; t < 2; t++) {
        int id = ids[t];
        const float4* zp = (const float4*)(Zall + (size_t)id * Pp);
        float4 z0 = zp[0], z1 = zp[1], z2 = zp[2], z3 = zp[3];
        float core = fp[0] * z0.x + fp[1] * z0.y + fp[2] * z0.z + fp[3] * z0.w;
        core += fp[4] * z1.x + fp[5] * z1.y + fp[6] * z1.z + fp[7] * z1.w;
        core += fp[8] * z2.x + fp[9] * z2.y + fp[10] * z2.z + fp[11] * z2.w;
        core += fp[12] * z3.x + fp[13] * z3.y + fp[14] * z3.z + fp[15] * z3.w;
        float dt = pdot - cdot[id];
        sims[t] = et * (core + dt) / 0.3f;
    }
    float mx = fmaxf(sims[0], sims[1]);
    mx = fmaxf(mx, __shfl_xor(mx, 1, 64));
    mx = fmaxf(mx, __shfl_xor(mx, 2, 64));
    float e0 = __expf(sims[0] - mx), e1 = __expf(sims[1] - mx);
    float se = e0 + e1;
    se += __shfl_xor(se, 1, 64);
    se += __shfl_xor(se, 2, 64);
    float isum = 1.f / se;
    float w0 = e0 * isum, w1 = e1 * isum;

    // bucket insert: record = int2(n, w bits), one 8B nt store each
    int p0 = atomicAdd(cnt + ids[0], 1);
    if (p0 < CAP) {
        long long pk = (unsigned)n | ((long long)(unsigned)__float_as_int(w0) << 32);
        __builtin_nontemporal_store(pk, (long long*)(rec + (size_t)ids[0] * CAP + p0));
    }
    int p1 = atomicAdd(cnt + ids[1], 1);
    if (p1 < CAP) {
        long long pk = (unsigned)n | ((long long)(unsigned)__float_as_int(w1) << 32);
        __builtin_nontemporal_store(pk, (long long*)(rec + (size_t)ids[1] * CAP + p1));
    }
}

// ---------------- K_prep: f_pts -> bf16 copy (15.4 MB, L2-resident in k2) ---
__global__ __launch_bounds__(256) void k_prep(const float* __restrict__ f,
                                              unsigned short* __restrict__ fb) {
    int i = blockIdx.x * 256 + threadIdx.x;       // 4 elems/thread, grid exact
    float4 v = ((const float4*)f)[i];
    ushort4 o;
    o.x = (unsigned short)f2bf(v.x);
    o.y = (unsigned short)f2bf(v.y);
    o.z = (unsigned short)f2bf(v.z);
    o.w = (unsigned short)f2bf(v.w);
    ((ushort4*)fb)[i] = o;
}

// ---- K2: gather-reduce per voxel (wave/voxel, lane=dim); weights in rec;
//          bf16 f_pts rows; writes bf16 msg ---------------------------------
__global__ __launch_bounds__(256) void k2_reduce(const unsigned short* __restrict__ fbf,
                                                 const int* __restrict__ cnt,
                                                 const int2* __restrict__ rec,
                                                 unsigned short* __restrict__ msgb) {
    int wv = threadIdx.x >> 6, lane = threadIdx.x & 63;
    int m = blockIdx.x * 4 + wv;
    if (m >= Mm) return;
    int c = cnt[m];
    if (c > CAP) c = CAP;
    const int4* r4 = (const int4*)(rec + (size_t)m * CAP);   // 2 records per int4
    float a0 = 0.f, a1 = 0.f, a2 = 0.f, a3 = 0.f, a4 = 0.f, a5 = 0.f, a6 = 0.f, a7 = 0.f;
    float s0 = 0.f, s1 = 0.f, s2 = 0.f, s3 = 0.f, s4 = 0.f, s5 = 0.f, s6 = 0.f, s7 = 0.f;
    for (int i0 = 0; i0 < c; i0 += 8) {
        int4 A = r4[(i0 >> 1) + 0];
        int4 B = r4[(i0 >> 1) + 1];
        int4 C = r4[(i0 >> 1) + 2];
        int4 D = r4[(i0 >> 1) + 3];
        if (i0 + 0 < c) { float w = __int_as_float(A.y); s0 += w; a0 = fmaf(w, bf2f(fbf[(size_t)A.x * Dd + lane]), a0); }
        if (i0 + 1 < c) { float w = __int_as_float(A.w); s1 += w; a1 = fmaf(w, bf2f(fbf[(size_t)A.z * Dd + lane]), a1); }
        if (i0 + 2 < c) { float w = __int_as_float(B.y); s2 += w; a2 = fmaf(w, bf2f(fbf[(size_t)B.x * Dd + lane]), a2); }
        if (i0 + 3 < c) { float w = __int_as_float(B.w); s3 += w; a3 = fmaf(w, bf2f(fbf[(size_t)B.z * Dd + lane]), a3); }
        if (i0 + 4 < c) { float w = __int_as_float(C.y); s4 += w; a4 = fmaf(w, bf2f(fbf[(size_t)C.x * Dd + lane]), a4); }
        if (i0 + 5 < c) { float w = __int_as_float(C.w); s5 += w; a5 = fmaf(w, bf2f(fbf[(size_t)C.z * Dd + lane]), a5); }
        if (i0 + 6 < c) { float w = __int_as_float(D.y); s6 += w; a6 = fmaf(w, bf2f(fbf[(size_t)D.x * Dd + lane]), a6); }
        if (i0 + 7 < c) { float w = __int_as_float(D.w); s7 += w; a7 = fmaf(w, bf2f(fbf[(size_t)D.z * Dd + lane]), a7); }
    }
    float acc = ((a0 + a1) + (a2 + a3)) + ((a4 + a5) + (a6 + a7));
    float wsum = ((s0 + s1) + (s2 + s3)) + ((s4 + s5) + (s6 + s7));
    msgb[(size_t)m * Dd + lane] = (unsigned short)f2bf(acc / (wsum + 1e-6f));
}

// ---------------- K_pack: weights -> bf16 MFMA B-fragment layout ------------
// frag f, lane l: 8 bf16 = W[o = t*16 + (l&15)][k = c*32 + (l>>4)*8 + j]
__global__ __launch_bounds__(256) void k_pack(const float* __restrict__ Wg1,
                                              const float* __restrict__ W_ih,
                                              const float* __restrict__ W_hh,
                                              const float* __restrict__ Wd1,
                                              const float* __restrict__ Wd2,
                                              short* __restrict__ wsW) {
    int idx = blockIdx.x * 256 + threadIdx.x;
    if (idx >= 86 * 64) return;
    int f = idx >> 6, lane = idx & 63;
    int lrow = lane & 15, lhi = lane >> 4;
    const float* src;
    int t, c, K;
    if (f < 8)       { int g = f;      t = g >> 2; c = g & 3;  src = Wg1;  K = 128; }
    else if (f < 32) { int g = f - 8;  t = g >> 1; c = g & 1;  src = W_ih; K = 64; }
    else if (f < 56) { int g = f - 32; t = g >> 1; c = g & 1;  src = W_hh; K = 64; }
    else if (f < 68) { int g = f - 56; t = g >> 1; c = g & 1;  src = Wd1;  K = 64; }
    else             { int g = f - 68; t = g / 3;  c = g % 3;  src = Wd2;  K = 96; }
    int o = t * 16 + lrow;
    int k0 = c * 32 + lhi * 8;
    short* dst = wsW + ((size_t)f * 64 + lane) * 8;
#pragma unroll
    for (int j = 0; j < 8; j++) dst[j] = f2bf(src[(size_t)o * K + k0 + j]);
}

// ---- K3: MFMA voxel pipeline, wave/16 voxels; phase-grouped B-frag loads ---
__global__ __launch_bounds__(256, 3) void k3_mfma(const float* __restrict__ z_latent,
                                                  const unsigned short* __restrict__ msgb,
                                                  const short* __restrict__ wsW,
                                                  const float* __restrict__ bg1,
                                                  const float* __restrict__ Wg2,
                                                  const float* __restrict__ bg2,
                                                  const float* __restrict__ b_ih,
                                                  const float* __restrict__ b_hh,
                                                  const float* __restrict__ ln_g,
                                                  const float* __restrict__ ln_b,
                                                  const float* __restrict__ bd1,
                                                  const float* __restrict__ bd2,
                                                  const float* __restrict__ Wd3,
                                                  const float* __restrict__ bd3,
                                                  const float* __restrict__ vacc,
                                                  float* __restrict__ out) {
    __shared__ float scr_all[4][16 * 97];    // wave-private 16x97 stripes, 24.8 KB
    int wv = threadIdx.x >> 6, lane = threadIdx.x & 63;
    int tile = blockIdx.x * 4 + wv;
    if (tile >= Mm / 16) return;             // no barriers below -> safe early exit
    int m0 = tile * 16;
    float* scr = scr_all[wv];
    int lrow = lane & 15;                    // A/B operand row, D column
    int lhi = lane >> 4;                     // D row quad

    // vals passthrough (exact path)
    if (lane < 16) {
        float v = vacc[m0 + lane];
        out[Mm + m0 + lane] = fminf(fmaxf(v, -2.f), 3.5f);
    }

    const bf16x8* WF = (const bf16x8*)wsW;
#define BFRAG(off) (WF[(off) * 64 + lane])

    // ---- A fragments: z (f32 convert), mg (bf16 direct load) ----
    bf16x8 za[2], ma[2];
    const float* zrow = z_latent + (size_t)(m0 + lrow) * Dd + lhi * 8;
    const bf16x8* mrow = (const bf16x8*)(msgb + (size_t)(m0 + lrow) * Dd + lhi * 8);
#pragma unroll
    for (int c = 0; c < 2; c++) {
        bf16x8 t0;
#pragma unroll
        for (int j = 0; j < 8; j++) t0[j] = f2bf(zrow[c * 32 + j]);
        za[c] = t0;
        ma[c] = mrow[c * 4];                 // c*32 ushorts = c*4 bf16x8
    }

    // ---- gate: grouped 8-frag load, then 8 MFMAs ----
    bf16x8 wgf[8];
#pragma unroll
    for (int j = 0; j < 8; j++) wgf[j] = BFRAG(j);
    f32x4 g0 = {0.f, 0.f, 0.f, 0.f}, g1 = {0.f, 0.f, 0.f, 0.f};
    bf16x8 gateA[4] = {za[0], za[1], ma[0], ma[1]};
#pragma unroll
    for (int c = 0; c < 4; c++) {
        g0 = __builtin_amdgcn_mfma_f32_16x16x32_bf16(gateA[c], wgf[c], g0, 0, 0, 0);
        g1 = __builtin_amdgcn_mfma_f32_16x16x32_bf16(gateA[c], wgf[4 + c], g1, 0, 0, 0);
    }
    float bgA = bg1[lrow], bgB = bg1[16 + lrow];
    float w2A = Wg2[lrow], w2B = Wg2[16 + lrow];
    float g[4];
#pragma unroll
    for (int r = 0; r < 4; r++) {
        float ga = fmaxf(g0[r] + bgA, 0.f) * w2A + fmaxf(g1[r] + bgB, 0.f) * w2B;
        ga += __shfl_xor(ga, 1, 64);
        ga += __shfl_xor(ga, 2, 64);
        ga += __shfl_xor(ga, 4, 64);
        ga += __shfl_xor(ga, 8, 64);
        g[r] = sigmoidf_(ga + bg2[0]);
    }

    // ---- GRU: 4 col-tiles; per-tile grouped 12-frag load, then 12 MFMAs ----
    float zn[4][4];                          // [t][r] z_new in C-layout
    float ps[4] = {0.f, 0.f, 0.f, 0.f}, pq[4] = {0.f, 0.f, 0.f, 0.f};
#pragma unroll
    for (int t = 0; t < 4; t++) {
        bf16x8 wt[12];
#pragma unroll
        for (int c = 0; c < 2; c++) {
            wt[0 + c]  = BFRAG(8 + t * 2 + c);            // ih r
            wt[2 + c]  = BFRAG(8 + (t + 4) * 2 + c);      // ih z
            wt[4 + c]  = BFRAG(8 + (t + 8) * 2 + c);      // ih n
            wt[6 + c]  = BFRAG(32 + t * 2 + c);           // hh r
            wt[8 + c]  = BFRAG(32 + (t + 4) * 2 + c);     // hh z
            wt[10 + c] = BFRAG(32 + (t + 8) * 2 + c);     // hh n
        }
        f32x4 Ar = {0.f, 0.f, 0.f, 0.f}, Az = Ar, An = Ar, Br = Ar, Bz = Ar, Bn = Ar;
#pragma unroll
        for (int c = 0; c < 2; c++) {
            Ar = __builtin_amdgcn_mfma_f32_16x16x32_bf16(ma[c], wt[0 + c], Ar, 0, 0, 0);
            Az = __builtin_amdgcn_mfma_f32_16x16x32_bf16(ma[c], wt[2 + c], Az, 0, 0, 0);
            An = __builtin_amdgcn_mfma_f32_16x16x32_bf16(ma[c], wt[4 + c], An, 0, 0, 0);
            Br = __builtin_amdgcn_mfma_f32_16x16x32_bf16(za[c], wt[6 + c], Br, 0, 0, 0);
            Bz = __builtin_amdgcn_mfma_f32_16x16x32_bf16(za[c], wt[8 + c], Bz, 0, 0, 0);
            Bn = __builtin_amdgcn_mfma_f32_16x16x32_bf16(za[c], wt[10 + c], Bn, 0, 0, 0);
        }
        int oc = t * 16 + lrow;
        float bir = b_ih[oc], biz = b_ih[64 + oc], bin = b_ih[128 + oc];
        float bhr = b_hh[oc], bhz = b_hh[64 + oc], bhn = b_hh[128 + oc];
#pragma unroll
        for (int r = 0; r < 4; r++) {
            int row = lhi * 4 + r;
            float zo = z_latent[(size_t)(m0 + row) * Dd + oc];
            float rr = sigmoidf_(Ar[r] + bir + Br[r] + bhr);
            float uu = sigmoidf_(Az[r] + biz + Bz[r] + bhz);
            float nnv = tanh_fast(An[r] + bin + rr * (Bn[r] + bhn));
            float hn = (1.f - uu) * nnv + uu * zo;
            float z2 = zo + g[r] * (hn - zo);
            zn[t][r] = z2;
            ps[r] += z2;
            pq[r] = fmaf(z2, z2, pq[r]);
        }
    }
    // LN stats: reduce over 64 cols
    float mu[4], rs[4];
#pragma unroll
    for (int r = 0; r < 4; r++) {
        float s = ps[r], q = pq[r];
        s += __shfl_xor(s, 1, 64); q += __shfl_xor(q, 1, 64);
        s += __shfl_xor(s, 2, 64); q += __shfl_xor(q, 2, 64);
        s += __shfl_xor(s, 4, 64); q += __shfl_xor(q, 4, 64);
        s += __shfl_xor(s, 8, 64); q += __shfl_xor(q, 8, 64);
        float m = s * (1.f / 64.f);
        float v = q * (1.f / 64.f) - m * m;
        mu[r] = m;
        rs[r] = rsqrtf(v + 1e-5f);
    }
    // x = LN(z_new)  -> LDS (C-layout write, stride 97 = conflict-free)
#pragma unroll
    for (int t = 0; t < 4; t++) {
        int o = t * 16 + lrow;
        float lg = ln_g[o], lb = ln_b[o];
#pragma unroll
        for (int r = 0; r < 4; r++)
            scr[(lhi * 4 + r) * 97 + o] = (zn[t][r] - mu[r]) * rs[r] * lg + lb;
    }
    __threadfence_block();                   // cross-lane LDS visibility in-wave

    // x -> A-frags for fc1
    bf16x8 xa[2];
#pragma unroll
    for (int c = 0; c < 2; c++) {
        bf16x8 tb;
#pragma unroll
        for (int j = 0; j < 8; j++) tb[j] = f2bf(scr[lrow * 97 + c * 32 + lhi * 8 + j]);
        xa[c] = tb;
    }
    // fc1: grouped 12-frag load, then 12 MFMAs
    bf16x8 wf1[12];
#pragma unroll
    for (int j = 0; j < 12; j++) wf1[j] = BFRAG(56 + j);
    f32x4 h1t[6];
#pragma unroll
    for (int t = 0; t < 6; t++) h1t[t] = (f32x4){0.f, 0.f, 0.f, 0.f};
#pragma unroll
    for (int t = 0; t < 6; t++)
#pragma unroll
        for (int c = 0; c < 2; c++)
            h1t[t] = __builtin_amdgcn_mfma_f32_16x16x32_bf16(xa[c], wf1[t * 2 + c], h1t[t], 0, 0, 0);
    float h1r[6][4];
#pragma unroll
    for (int t = 0; t < 6; t++) {
        float bb = bd1[t * 16 + lrow];
#pragma unroll
        for (int r = 0; r < 4; r++) {
            h1r[t][r] = fmaxf(h1t[t][r] + bb, 0.f);
            scr[(lhi * 4 + r) * 97 + t * 16 + lrow] = h1r[t][r];   // h1 -> LDS
        }
    }
    __threadfence_block();

    // h1 -> A-frags for fc2 (K=96, 3 chunks)
    bf16x8 ha[3];
#pragma unroll
    for (int c = 0; c < 3; c++) {
        bf16x8 tb;
#pragma unroll
        for (int j = 0; j < 8; j++) tb[j] = f2bf(scr[lrow * 97 + c * 32 + lhi * 8 + j]);
        ha[c] = tb;
    }
    // fc2: grouped 18-frag load, then 18 MFMAs; + residual + fc3
    bf16x8 wf2[18];
#pragma unroll
    for (int j = 0; j < 18; j++) wf2[j] = BFRAG(68 + j);
    f32x4 o2[6];
#pragma unroll
    for (int t = 0; t < 6; t++) o2[t] = (f32x4){0.f, 0.f, 0.f, 0.f};
#pragma unroll
    for (int t = 0; t < 6; t++)
#pragma unroll
        for (int c = 0; c < 3; c++)
            o2[t] = __builtin_amdgcn_mfma_f32_16x16x32_bf16(ha[c], wf2[t * 3 + c], o2[t], 0, 0, 0);
    float pacc[4] = {0.f, 0.f, 0.f, 0.f};
#pragma unroll
    for (int t = 0; t < 6; t++) {
        int o = t * 16 + lrow;
        float bb = bd2[o], w3 = Wd3[o];
#pragma unroll
        for (int r = 0; r < 4; r++) {
            float hd2 = h1r[t][r] + fmaxf(o2[t][r] + bb, 0.f);
            pacc[r] = fmaf(hd2, w3, pacc[r]);
        }
    }
#pragma unroll
    for (int r = 0; r < 4; r++) {
        float s = pacc[r];
        s += __shfl_xor(s, 1, 64);
        s += __shfl_xor(s, 2, 64);
        s += __shfl_xor(s, 4, 64);
        s += __shfl_xor(s, 8, 64);
        if (lrow == 0) out[m0 + lhi * 4 + r] = sigmoidf_(s + bd3[0]);
    }
#undef BFRAG
}

extern "C" void kernel_launch(void* const* d_in, const int* in_sizes, int n_in,
                              void* d_out, int out_size, void* d_ws, size_t ws_size,
                              hipStream_t stream) {
    const float* pts      = (const float*)d_in[0];
    const float* f_pts    = (const float*)d_in[1];
    const float* z_lat    = (const float*)d_in[2];
    const float* vals     = (const float*)d_in[3];
    const float* centers  = (const float*)d_in[4];
    const float* Wf       = (const float*)d_in[5];
    const float* Wz       = (const float*)d_in[6];
    const float* w_delta  = (const float*)d_in[7];
    const float* b_delta  = (const float*)d_in[8];
    const float* log_temp = (const float*)d_in[9];
    const float* W_ih     = (const float*)d_in[10];
    const float* W_hh     = (const float*)d_in[11];
    const float* b_ih     = (const float*)d_in[12];
    const float* b_hh     = (const float*)d_in[13];
    const float* Wg1      = (const float*)d_in[14];
    const float* bg1      = (const float*)d_in[15];
    const float* Wg2      = (const float*)d_in[16];
    const float* bg2      = (const float*)d_in[17];
    const float* ln_g     = (const float*)d_in[18];
    const float* ln_b     = (const float*)d_in[19];
    const float* Wd1      = (const float*)d_in[20];
    const float* bd1      = (const float*)d_in[21];
    const float* Wd2      = (const float*)d_in[22];
    const float* bd2      = (const float*)d_in[23];
    const float* Wd3      = (const float*)d_in[24];
    const float* bd3      = (const float*)d_in[25];
    const int*   keys     = (const int*)d_in[26];
    const int*   cand     = (const int*)d_in[27];
    float* out = (float*)d_out;

    // ws layout (floats). fbf overlaps dead Zall (Zall live k0-k1; fbf k_prep-k2).
    float* ws = (float*)d_ws;
    short* wsW = (short*)ws;                                  // 88 KB (k_pack -> k3)
    float* Zall = ws + 32768;                                 // M*16 (k0 -> k1)
    unsigned short* fbf = (unsigned short*)(ws + 32768);      // N*64 bf16 (overlaps Zall)
    float* base = ws + 32768 + (size_t)Nn * Dd / 2;           // end of fbf region
    unsigned short* msgb = (unsigned short*)base;             // M*64 bf16
    float* vacc = base + (size_t)Mm * Dd / 2;                 // M
    int*   cnt  = (int*)(vacc + Mm);                          // M
    int2*  rec  = (int2*)(cnt + Mm);                          // M*CAP int2 (32 MB)
    float* cdot = (float*)((int*)rec + (size_t)Mm * CAP * 2); // M
    int*   lut  = (int*)(cdot + Mm);                          // 4097   total ~61.5 MB

    hipMemsetAsync(cnt, 0, sizeof(int) * Mm, stream);
    hipMemcpyAsync(vacc, vals, sizeof(float) * Mm, hipMemcpyDeviceToDevice, stream);

    k0_projz<<<(Mm * 4 + 255) / 256, 256, 0, stream>>>(z_lat, Wz, centers, w_delta,
                                                       keys, Zall, cdot, lut);
    k1_route<<<Nn / 64, 256, 0, stream>>>(pts, f_pts, Wf, w_delta, b_delta, log_temp,
                                          keys, cand, Zall, cdot, lut, vacc, cnt, rec);
    k_pack<<<(86 * 64 + 255) / 256, 256, 0, stream>>>(Wg1, W_ih, W_hh, Wd1, Wd2, wsW);
    k_prep<<<(Nn * Dd / 4) / 256, 256, 0, stream>>>(f_pts, fbf);   // after k1: fbf over Zall
    k2_reduce<<<(Mm + 3) / 4, 256, 0, stream>>>(fbf, cnt, rec, msgb);
    k3_mfma<<<(Mm / 16 + 3) / 4, 256, 0, stream>>>(z_lat, msgb, wsW, bg1, Wg2, bg2,
                                                   b_ih, b_hh, ln_g, ln_b, bd1, bd2,
                                                   Wd3, bd3, vacc, out);
}

// Round 8
// 358.473 us; speedup vs baseline: 1.3942x; 1.0441x over previous
//
#include <hip/hip_runtime.h>
#include <math.h>

#define Nn 120000
#define Kk 8
#define Dd 64
#define Mm 100000
#define Pp 16
#define HGg 32
#define HDd 96
#define CAP 40   // per-voxel bucket capacity; actual max ~27-31
#define LUTB 12  // prefix bits for 2-level search (keys < 2^30)

typedef __attribute__((ext_vector_type(8))) short bf16x8;
typedef __attribute__((ext_vector_type(4))) float f32x4;

__device__ __forceinline__ float sigmoidf_(float x) { return 1.f / (1.f + __expf(-x)); }
__device__ __forceinline__ float tanh_fast(float x) {
    float e = __expf(2.f * x);
    return 1.f - 2.f / (e + 1.f);
}
// f32 -> bf16 round-to-nearest-even
__device__ __forceinline__ short f2bf(float f) {
    unsigned u = __float_as_uint(f);
    unsigned r = (u + 0x7fffu + ((u >> 16) & 1u)) >> 16;
    return (short)r;
}
__device__ __forceinline__ float bf2f(unsigned short u) {
    return __uint_as_float(((unsigned)u) << 16);
}

// -- K0: 4 lanes/voxel. Packed row: [16 bf16 proj | f32 cdot | pad] = 64 B;
//        search LUT over keys ----------------------------------------------
__global__ __launch_bounds__(256) void k0_projz(const float* __restrict__ z,
                                                const float* __restrict__ Wz,
                                                const float* __restrict__ centers,
                                                const float* __restrict__ w_delta,
                                                const int* __restrict__ keys,
                                                unsigned* __restrict__ Zpk,
                                                int* __restrict__ lut) {
    int g = threadIdx.x & 3;
    int m = blockIdx.x * 64 + (threadIdx.x >> 2);
    if (m >= Mm) return;
    if (g == 0 && m <= (1 << LUTB)) {
        int target = m << (30 - LUTB);
        int lo = 0, hi = Mm;
        while (lo < hi) {
            int mid = (lo + hi) >> 1;
            if (keys[mid] < target) lo = mid + 1; else hi = mid;
        }
        lut[m] = lo;
    }
    // partial dots over this lane's 16-dim quarter
    const float4* zr = (const float4*)(z + (size_t)m * Dd + g * 16);
    float4 q0 = zr[0], q1 = zr[1], q2 = zr[2], q3 = zr[3];
    float acc[Pp];
#pragma unroll
    for (int p = 0; p < Pp; p++) {
        const float4* w = (const float4*)(Wz + (size_t)p * Dd + g * 16);
        float4 w0 = w[0], w1 = w[1], w2 = w[2], w3 = w[3];
        float s = q0.x * w0.x + q0.y * w0.y + q0.z * w0.z + q0.w * w0.w;
        s += q1.x * w1.x + q1.y * w1.y + q1.z * w1.z + q1.w * w1.w;
        s += q2.x * w2.x + q2.y * w2.y + q2.z * w2.z + q2.w * w2.w;
        s += q3.x * w3.x + q3.y * w3.y + q3.z * w3.z + q3.w * w3.w;
        acc[p] = s;
    }
#pragma unroll
    for (int p = 0; p < Pp; p++) {
        acc[p] += __shfl_xor(acc[p], 1, 64);
        acc[p] += __shfl_xor(acc[p], 2, 64);
    }
    float ss = 0.f;
#pragma unroll
    for (int p = 0; p < Pp; p++) ss = fmaf(acc[p], acc[p], ss);
    float inv = 1.f / (sqrtf(ss) + 1e-6f);
    unsigned* row = Zpk + (size_t)m * 16;        // 64 B row
    if (g < 2) {
        // lane g packs bf16 elements [g*8 .. g*8+7] into one uint4
        uint4 o;
        unsigned w[4];
#pragma unroll
        for (int j = 0; j < 4; j++) {
            float v0 = acc[g * 8 + 2 * j] * inv;
            float v1 = acc[g * 8 + 2 * j + 1] * inv;
            w[j] = (unsigned)(unsigned short)f2bf(v0)
                 | ((unsigned)(unsigned short)f2bf(v1) << 16);
        }
        o.x = w[0]; o.y = w[1]; o.z = w[2]; o.w = w[3];
        ((uint4*)row)[g] = o;
    } else if (g == 2) {
        float cd = centers[3 * m] * w_delta[0] + centers[3 * m + 1] * w_delta[1]
                 + centers[3 * m + 2] * w_delta[2];
        row[8] = __float_as_uint(cd);
    }
}

// --- K1: 8 lanes/point. search on g==0; Fp via 8-way group dots;
//         1 candidate/lane from one 64B packed row; group softmax; insert ---
__global__ __launch_bounds__(256) void k1_route(const float* __restrict__ pts,
                                                const float* __restrict__ f_pts,
                                                const float* __restrict__ Wf,
                                                const float* __restrict__ w_delta,
                                                const float* __restrict__ b_delta,
                                                const float* __restrict__ log_temp,
                                                const int* __restrict__ keys,
                                                const int* __restrict__ cand,
                                                const unsigned* __restrict__ Zpk,
                                                const int* __restrict__ lut,
                                                float* __restrict__ vacc,
                                                int* __restrict__ cnt,
                                                int2* __restrict__ rec) {
    int g = threadIdx.x & 7;                         // lane-in-group (= candidate k)
    int n = blockIdx.x * 32 + (threadIdx.x >> 3);    // grid = 3750 exact

    float px = pts[3 * n], py = pts[3 * n + 1], pz = pts[3 * n + 2];
    int myid = cand[(size_t)n * Kk + g];             // coalesced

    if (g == 0) {
        // IEEE f32 divide then floor, matching the reference exactly
        int ix = (int)floorf(px / 0.1f);
        int iy = (int)floorf(py / 0.1f);
        int iz = (int)floorf(pz / 0.1f);
        int h = ((ix + 512) << 20) ^ ((iy + 512) << 10) ^ (iz + 512);
        int pfx = h >> (30 - LUTB);
        int lo = lut[pfx], hi = lut[pfx + 1];
        while (lo < hi) {
            int mid = (lo + hi) >> 1;
            if (keys[mid] < h) lo = mid + 1; else hi = mid;
        }
        int vi = lo < (Mm - 1) ? lo : (Mm - 1);
        atomicAdd(vacc + vi, 0.5f);
    }

    // ---- Fp partial dots over this lane's 8-float slice ----
    const float4* fr = (const float4*)(f_pts + (size_t)n * Dd + g * 8);
    float4 q0 = fr[0], q1 = fr[1];
    float fp[Pp];
#pragma unroll
    for (int p = 0; p < Pp; p++) {
        const float4* w = (const float4*)(Wf + (size_t)p * Dd + g * 8);
        float4 w0 = w[0], w1 = w[1];
        float s = q0.x * w0.x + q0.y * w0.y + q0.z * w0.z + q0.w * w0.w;
        s += q1.x * w1.x + q1.y * w1.y + q1.z * w1.z + q1.w * w1.w;
        fp[p] = s;
    }
#pragma unroll
    for (int p = 0; p < Pp; p++) {
        fp[p] += __shfl_xor(fp[p], 1, 64);
        fp[p] += __shfl_xor(fp[p], 2, 64);
        fp[p] += __shfl_xor(fp[p], 4, 64);
    }
    float ss = 0.f;
#pragma unroll
    for (int p = 0; p < Pp; p++) ss = fmaf(fp[p], fp[p], ss);
    float inv = 1.f / (sqrtf(ss) + 1e-6f);
#pragma unroll
    for (int p = 0; p < Pp; p++) fp[p] *= inv;

    float et = expf(log_temp[0]);
    float pdot = px * w_delta[0] + py * w_delta[1] + pz * w_delta[2] + b_delta[0];

    // ---- this lane's candidate: one 64B row (3 loads, 1 sector) ----
    const uint4* zp = (const uint4*)(Zpk + (size_t)myid * 16);
    uint4 A = zp[0], B = zp[1];
    float cd = __uint_as_float(Zpk[(size_t)myid * 16 + 8]);
    unsigned uw[8] = {A.x, A.y, A.z, A.w, B.x, B.y, B.z, B.w};
    float core = 0.f;
#pragma unroll
    for (int j = 0; j < 8; j++) {
        float lo = __uint_as_float(uw[j] << 16);
        float hi = __uint_as_float(uw[j] & 0xffff0000u);
        core = fmaf(fp[2 * j], lo, core);
        core = fmaf(fp[2 * j + 1], hi, core);
    }
    float sim = et * (core + pdot - cd) / 0.3f;

    // softmax over the 8 lanes of the group
    float mx = sim;
    mx = fmaxf(mx, __shfl_xor(mx, 1, 64));
    mx = fmaxf(mx, __shfl_xor(mx, 2, 64));
    mx = fmaxf(mx, __shfl_xor(mx, 4, 64));
    float e = __expf(sim - mx);
    float se = e;
    se += __shfl_xor(se, 1, 64);
    se += __shfl_xor(se, 2, 64);
    se += __shfl_xor(se, 4, 64);
    float w = e / se;

    // bucket insert: record = int2(n, w bits), one 8B nt store
    int pos = atomicAdd(cnt + myid, 1);
    if (pos < CAP) {
        long long pk = (unsigned)n | ((long long)(unsigned)__float_as_int(w) << 32);
        __builtin_nontemporal_store(pk, (long long*)(rec + (size_t)myid * CAP + pos));
    }
}

// ---------------- K_prep: f_pts -> int8 (clamp +-4, x32); 7.7 MB -----------
__global__ __launch_bounds__(256) void k_prep(const float* __restrict__ f,
                                              signed char* __restrict__ f8) {
    int i = blockIdx.x * 256 + threadIdx.x;       // 8 elems/thread, grid = 3750 exact
    const float4* src = (const float4*)f + (size_t)i * 2;
    float4 a = src[0], b = src[1];
    float v[8] = {a.x, a.y, a.z, a.w, b.x, b.y, b.z, b.w};
    unsigned lo = 0, hi = 0;
#pragma unroll
    for (int j = 0; j < 4; j++) {
        int q = (int)rintf(fminf(fmaxf(v[j], -4.f), 4.f) * 32.f);
        lo |= ((unsigned)q & 0xffu) << (8 * j);
    }
#pragma unroll
    for (int j = 0; j < 4; j++) {
        int q = (int)rintf(fminf(fmaxf(v[4 + j], -4.f), 4.f) * 32.f);
        hi |= ((unsigned)q & 0xffu) << (8 * j);
    }
    ((int2*)f8)[i] = make_int2((int)lo, (int)hi);
}

// ---- K2: gather-reduce per voxel (wave/voxel, lane=dim); int8 rows = 1
//          sector per gather; weights in rec; writes bf16 msg ---------------
__global__ __launch_bounds__(256) void k2_reduce(const signed char* __restrict__ f8,
                                                 const int* __restrict__ cnt,
                                                 const int2* __restrict__ rec,
                                                 unsigned short* __restrict__ msgb) {
    int wv = threadIdx.x >> 6, lane = threadIdx.x & 63;
    int m = blockIdx.x * 4 + wv;
    if (m >= Mm) return;
    int c = cnt[m];
    if (c > CAP) c = CAP;
    const int4* r4 = (const int4*)(rec + (size_t)m * CAP);   // 2 records per int4
    float a0 = 0.f, a1 = 0.f, a2 = 0.f, a3 = 0.f, a4 = 0.f, a5 = 0.f, a6 = 0.f, a7 = 0.f;
    float s0 = 0.f, s1 = 0.f, s2 = 0.f, s3 = 0.f, s4 = 0.f, s5 = 0.f, s6 = 0.f, s7 = 0.f;
    for (int i0 = 0; i0 < c; i0 += 8) {
        int4 A = r4[(i0 >> 1) + 0];
        int4 B = r4[(i0 >> 1) + 1];
        int4 C = r4[(i0 >> 1) + 2];
        int4 D = r4[(i0 >> 1) + 3];
        if (i0 + 0 < c) { float w = __int_as_float(A.y); s0 += w; a0 = fmaf(w, (float)f8[(size_t)A.x * Dd + lane], a0); }
        if (i0 + 1 < c) { float w = __int_as_float(A.w); s1 += w; a1 = fmaf(w, (float)f8[(size_t)A.z * Dd + lane], a1); }
        if (i0 + 2 < c) { float w = __int_as_float(B.y); s2 += w; a2 = fmaf(w, (float)f8[(size_t)B.x * Dd + lane], a2); }
        if (i0 + 3 < c) { float w = __int_as_float(B.w); s3 += w; a3 = fmaf(w, (float)f8[(size_t)B.z * Dd + lane], a3); }
        if (i0 + 4 < c) { float w = __int_as_float(C.y); s4 += w; a4 = fmaf(w, (float)f8[(size_t)C.x * Dd + lane], a4); }
        if (i0 + 5 < c) { float w = __int_as_float(C.w); s5 += w; a5 = fmaf(w, (float)f8[(size_t)C.z * Dd + lane], a5); }
        if (i0 + 6 < c) { float w = __int_as_float(D.y); s6 += w; a6 = fmaf(w, (float)f8[(size_t)D.x * Dd + lane], a6); }
        if (i0 + 7 < c) { float w = __int_as_float(D.w); s7 += w; a7 = fmaf(w, (float)f8[(size_t)D.z * Dd + lane], a7); }
    }
    float acc = (((a0 + a1) + (a2 + a3)) + ((a4 + a5) + (a6 + a7))) * 0.03125f;
    float wsum = ((s0 + s1) + (s2 + s3)) + ((s4 + s5) + (s6 + s7));
    msgb[(size_t)m * Dd + lane] = (unsigned short)f2bf(acc / (wsum + 1e-6f));
}

// ---------------- K_pack: weights -> bf16 MFMA B-fragment layout ------------
__global__ __launch_bounds__(256) void k_pack(const float* __restrict__ Wg1,
                                              const float* __restrict__ W_ih,
                                              const float* __restrict__ W_hh,
                                              const float* __restrict__ Wd1,
                                              const float* __restrict__ Wd2,
                                              short* __restrict__ wsW) {
    int idx = blockIdx.x * 256 + threadIdx.x;
    if (idx >= 86 * 64) return;
    int f = idx >> 6, lane = idx & 63;
    int lrow = lane & 15, lhi = lane >> 4;
    const float* src;
    int t, c, K;
    if (f < 8)       { int g = f;      t = g >> 2; c = g & 3;  src = Wg1;  K = 128; }
    else if (f < 32) { int g = f - 8;  t = g >> 1; c = g & 1;  src = W_ih; K = 64; }
    else if (f < 56) { int g = f - 32; t = g >> 1; c = g & 1;  src = W_hh; K = 64; }
    else if (f < 68) { int g = f - 56; t = g >> 1; c = g & 1;  src = Wd1;  K = 64; }
    else             { int g = f - 68; t = g / 3;  c = g % 3;  src = Wd2;  K = 96; }
    int o = t * 16 + lrow;
    int k0 = c * 32 + lhi * 8;
    short* dst = wsW + ((size_t)f * 64 + lane) * 8;
#pragma unroll
    for (int j = 0; j < 8; j++) dst[j] = f2bf(src[(size_t)o * K + k0 + j]);
}

// ---- K3: MFMA voxel pipeline, wave/16 voxels; phase-grouped B-frag loads ---
__global__ __launch_bounds__(256, 3) void k3_mfma(const float* __restrict__ z_latent,
                                                  const unsigned short* __restrict__ msgb,
                                                  const short* __restrict__ wsW,
                                                  const float* __restrict__ bg1,
                                                  const float* __restrict__ Wg2,
                                                  const float* __restrict__ bg2,
                                                  const float* __restrict__ b_ih,
                                                  const float* __restrict__ b_hh,
                                                  const float* __restrict__ ln_g,
                                                  const float* __restrict__ ln_b,
                                                  const float* __restrict__ bd1,
                                                  const float* __restrict__ bd2,
                                                  const float* __restrict__ Wd3,
                                                  const float* __restrict__ bd3,
                                                  const float* __restrict__ vacc,
                                                  float* __restrict__ out) {
    __shared__ float scr_all[4][16 * 97];    // wave-private 16x97 stripes, 24.8 KB
    int wv = threadIdx.x >> 6, lane = threadIdx.x & 63;
    int tile = blockIdx.x * 4 + wv;
    if (tile >= Mm / 16) return;             // no barriers below -> safe early exit
    int m0 = tile * 16;
    float* scr = scr_all[wv];
    int lrow = lane & 15;
    int lhi = lane >> 4;

    if (lane < 16) {
        float v = vacc[m0 + lane];
        out[Mm + m0 + lane] = fminf(fmaxf(v, -2.f), 3.5f);
    }

    const bf16x8* WF = (const bf16x8*)wsW;
#define BFRAG(off) (WF[(off) * 64 + lane])

    bf16x8 za[2], ma[2];
    const float* zrow = z_latent + (size_t)(m0 + lrow) * Dd + lhi * 8;
    const bf16x8* mrow = (const bf16x8*)(msgb + (size_t)(m0 + lrow) * Dd + lhi * 8);
#pragma unroll
    for (int c = 0; c < 2; c++) {
        bf16x8 t0;
#pragma unroll
        for (int j = 0; j < 8; j++) t0[j] = f2bf(zrow[c * 32 + j]);
        za[c] = t0;
        ma[c] = mrow[c * 4];
    }

    // ---- gate ----
    bf16x8 wgf[8];
#pragma unroll
    for (int j = 0; j < 8; j++) wgf[j] = BFRAG(j);
    f32x4 g0 = {0.f, 0.f, 0.f, 0.f}, g1 = {0.f, 0.f, 0.f, 0.f};
    bf16x8 gateA[4] = {za[0], za[1], ma[0], ma[1]};
#pragma unroll
    for (int c = 0; c < 4; c++) {
        g0 = __builtin_amdgcn_mfma_f32_16x16x32_bf16(gateA[c], wgf[c], g0, 0, 0, 0);
        g1 = __builtin_amdgcn_mfma_f32_16x16x32_bf16(gateA[c], wgf[4 + c], g1, 0, 0, 0);
    }
    float bgA = bg1[lrow], bgB = bg1[16 + lrow];
    float w2A = Wg2[lrow], w2B = Wg2[16 + lrow];
    float g[4];
#pragma unroll
    for (int r = 0; r < 4; r++) {
        float ga = fmaxf(g0[r] + bgA, 0.f) * w2A + fmaxf(g1[r] + bgB, 0.f) * w2B;
        ga += __shfl_xor(ga, 1, 64);
        ga += __shfl_xor(ga, 2, 64);
        ga += __shfl_xor(ga, 4, 64);
        ga += __shfl_xor(ga, 8, 64);
        g[r] = sigmoidf_(ga + bg2[0]);
    }

    // ---- GRU ----
    float zn[4][4];
    float ps[4] = {0.f, 0.f, 0.f, 0.f}, pq[4] = {0.f, 0.f, 0.f, 0.f};
#pragma unroll
    for (int t = 0; t < 4; t++) {
        bf16x8 wt[12];
#pragma unroll
        for (int c = 0; c < 2; c++) {
            wt[0 + c]  = BFRAG(8 + t * 2 + c);
            wt[2 + c]  = BFRAG(8 + (t + 4) * 2 + c);
            wt[4 + c]  = BFRAG(8 + (t + 8) * 2 + c);
            wt[6 + c]  = BFRAG(32 + t * 2 + c);
            wt[8 + c]  = BFRAG(32 + (t + 4) * 2 + c);
            wt[10 + c] = BFRAG(32 + (t + 8) * 2 + c);
        }
        f32x4 Ar = {0.f, 0.f, 0.f, 0.f}, Az = Ar, An = Ar, Br = Ar, Bz = Ar, Bn = Ar;
#pragma unroll
        for (int c = 0; c < 2; c++) {
            Ar = __builtin_amdgcn_mfma_f32_16x16x32_bf16(ma[c], wt[0 + c], Ar, 0, 0, 0);
            Az = __builtin_amdgcn_mfma_f32_16x16x32_bf16(ma[c], wt[2 + c], Az, 0, 0, 0);
            An = __builtin_amdgcn_mfma_f32_16x16x32_bf16(ma[c], wt[4 + c], An, 0, 0, 0);
            Br = __builtin_amdgcn_mfma_f32_16x16x32_bf16(za[c], wt[6 + c], Br, 0, 0, 0);
            Bz = __builtin_amdgcn_mfma_f32_16x16x32_bf16(za[c], wt[8 + c], Bz, 0, 0, 0);
            Bn = __builtin_amdgcn_mfma_f32_16x16x32_bf16(za[c], wt[10 + c], Bn, 0, 0, 0);
        }
        int oc = t * 16 + lrow;
        float bir = b_ih[oc], biz = b_ih[64 + oc], bin = b_ih[128 + oc];
        float bhr = b_hh[oc], bhz = b_hh[64 + oc], bhn = b_hh[128 + oc];
#pragma unroll
        for (int r = 0; r < 4; r++) {
            int row = lhi * 4 + r;
            float zo = z_latent[(size_t)(m0 + row) * Dd + oc];
            float rr = sigmoidf_(Ar[r] + bir + Br[r] + bhr);
            float uu = sigmoidf_(Az[r] + biz + Bz[r] + bhz);
            float nnv = tanh_fast(An[r] + bin + rr * (Bn[r] + bhn));
            float hn = (1.f - uu) * nnv + uu * zo;
            float z2 = zo + g[r] * (hn - zo);
            zn[t][r] = z2;
            ps[r] += z2;
            pq[r] = fmaf(z2, z2, pq[r]);
        }
    }
    float mu[4], rs[4];
#pragma unroll
    for (int r = 0; r < 4; r++) {
        float s = ps[r], q = pq[r];
        s += __shfl_xor(s, 1, 64); q += __shfl_xor(q, 1, 64);
        s += __shfl_xor(s, 2, 64); q += __shfl_xor(q, 2, 64);
        s += __shfl_xor(s, 4, 64); q += __shfl_xor(q, 4, 64);
        s += __shfl_xor(s, 8, 64); q += __shfl_xor(q, 8, 64);
        float m = s * (1.f / 64.f);
        float v = q * (1.f / 64.f) - m * m;
        mu[r] = m;
        rs[r] = rsqrtf(v + 1e-5f);
    }
#pragma unroll
    for (int t = 0; t < 4; t++) {
        int o = t * 16 + lrow;
        float lg = ln_g[o], lb = ln_b[o];
#pragma unroll
        for (int r = 0; r < 4; r++)
            scr[(lhi * 4 + r) * 97 + o] = (zn[t][r] - mu[r]) * rs[r] * lg + lb;
    }
    __threadfence_block();

    bf16x8 xa[2];
#pragma unroll
    for (int c = 0; c < 2; c++) {
        bf16x8 tb;
#pragma unroll
        for (int j = 0; j < 8; j++) tb[j] = f2bf(scr[lrow * 97 + c * 32 + lhi * 8 + j]);
        xa[c] = tb;
    }
    bf16x8 wf1[12];
#pragma unroll
    for (int j = 0; j < 12; j++) wf1[j] = BFRAG(56 + j);
    f32x4 h1t[6];
#pragma unroll
    for (int t = 0; t < 6; t++) h1t[t] = (f32x4){0.f, 0.f, 0.f, 0.f};
#pragma unroll
    for (int t = 0; t < 6; t++)
#pragma unroll
        for (int c = 0; c < 2; c++)
            h1t[t] = __builtin_amdgcn_mfma_f32_16x16x32_bf16(xa[c], wf1[t * 2 + c], h1t[t], 0, 0, 0);
    float h1r[6][4];
#pragma unroll
    for (int t = 0; t < 6; t++) {
        float bb = bd1[t * 16 + lrow];
#pragma unroll
        for (int r = 0; r < 4; r++) {
            h1r[t][r] = fmaxf(h1t[t][r] + bb, 0.f);
            scr[(lhi * 4 + r) * 97 + t * 16 + lrow] = h1r[t][r];
        }
    }
    __threadfence_block();

    bf16x8 ha[3];
#pragma unroll
    for (int c = 0; c < 3; c++) {
        bf16x8 tb;
#pragma unroll
        for (int j = 0; j < 8; j++) tb[j] = f2bf(scr[lrow * 97 + c * 32 + lhi * 8 + j]);
        ha[c] = tb;
    }
    bf16x8 wf2[18];
#pragma unroll
    for (int j = 0; j < 18; j++) wf2[j] = BFRAG(68 + j);
    f32x4 o2[6];
#pragma unroll
    for (int t = 0; t < 6; t++) o2[t] = (f32x4){0.f, 0.f, 0.f, 0.f};
#pragma unroll
    for (int t = 0; t < 6; t++)
#pragma unroll
        for (int c = 0; c < 3; c++)
            o2[t] = __builtin_amdgcn_mfma_f32_16x16x32_bf16(ha[c], wf2[t * 3 + c], o2[t], 0, 0, 0);
    float pacc[4] = {0.f, 0.f, 0.f, 0.f};
#pragma unroll
    for (int t = 0; t < 6; t++) {
        int o = t * 16 + lrow;
        float bb = bd2[o], w3 = Wd3[o];
#pragma unroll
        for (int r = 0; r < 4; r++) {
            float hd2 = h1r[t][r] + fmaxf(o2[t][r] + bb, 0.f);
            pacc[r] = fmaf(hd2, w3, pacc[r]);
        }
    }
#pragma unroll
    for (int r = 0; r < 4; r++) {
        float s = pacc[r];
        s += __shfl_xor(s, 1, 64);
        s += __shfl_xor(s, 2, 64);
        s += __shfl_xor(s, 4, 64);
        s += __shfl_xor(s, 8, 64);
        if (lrow == 0) out[m0 + lhi * 4 + r] = sigmoidf_(s + bd3[0]);
    }
#undef BFRAG
}

extern "C" void kernel_launch(void* const* d_in, const int* in_sizes, int n_in,
                              void* d_out, int out_size, void* d_ws, size_t ws_size,
                              hipStream_t stream) {
    const float* pts      = (const float*)d_in[0];
    const float* f_pts    = (const float*)d_in[1];
    const float* z_lat    = (const float*)d_in[2];
    const float* vals     = (const float*)d_in[3];
    const float* centers  = (const float*)d_in[4];
    const float* Wf       = (const float*)d_in[5];
    const float* Wz       = (const float*)d_in[6];
    const float* w_delta  = (const float*)d_in[7];
    const float* b_delta  = (const float*)d_in[8];
    const float* log_temp = (const float*)d_in[9];
    const float* W_ih     = (const float*)d_in[10];
    const float* W_hh     = (const float*)d_in[11];
    const float* b_ih     = (const float*)d_in[12];
    const float* b_hh     = (const float*)d_in[13];
    const float* Wg1      = (const float*)d_in[14];
    const float* bg1      = (const float*)d_in[15];
    const float* Wg2      = (const float*)d_in[16];
    const float* bg2      = (const float*)d_in[17];
    const float* ln_g     = (const float*)d_in[18];
    const float* ln_b     = (const float*)d_in[19];
    const float* Wd1      = (const float*)d_in[20];
    const float* bd1      = (const float*)d_in[21];
    const float* Wd2      = (const float*)d_in[22];
    const float* bd2      = (const float*)d_in[23];
    const float* Wd3      = (const float*)d_in[24];
    const float* bd3      = (const float*)d_in[25];
    const int*   keys     = (const int*)d_in[26];
    const int*   cand     = (const int*)d_in[27];
    float* out = (float*)d_out;

    // ws layout. Zpk (k0->k1, 6.4 MB) and f8 (k_prep->k2, 7.7 MB) share a
    // 7.7 MB region (Zpk dead before k_prep runs).
    float* ws = (float*)d_ws;
    short* wsW = (short*)ws;                                  // 88 KB (k_pack -> k3)
    unsigned* Zpk = (unsigned*)(ws + 32768);                  // M*16 uints
    signed char* f8 = (signed char*)(ws + 32768);             // N*64 int8 (overlaps Zpk)
    float* base = ws + 32768 + 1920000;                       // end of shared region
    unsigned short* msgb = (unsigned short*)base;             // M*64 bf16
    float* vacc = base + (size_t)Mm * Dd / 2;                 // M
    int*   cnt  = (int*)(vacc + Mm);                          // M
    int2*  rec  = (int2*)(cnt + Mm);                          // M*CAP int2 (32 MB)
    int*   lut  = (int*)((int*)rec + (size_t)Mm * CAP * 2);   // 4097  total ~53.5 MB

    hipMemsetAsync(cnt, 0, sizeof(int) * Mm, stream);
    hipMemcpyAsync(vacc, vals, sizeof(float) * Mm, hipMemcpyDeviceToDevice, stream);

    k0_projz<<<(Mm * 4 + 255) / 256, 256, 0, stream>>>(z_lat, Wz, centers, w_delta,
                                                       keys, Zpk, lut);
    k1_route<<<Nn / 32, 256, 0, stream>>>(pts, f_pts, Wf, w_delta, b_delta, log_temp,
                                          keys, cand, Zpk, lut, vacc, cnt, rec);
    k_pack<<<(86 * 64 + 255) / 256, 256, 0, stream>>>(Wg1, W_ih, W_hh, Wd1, Wd2, wsW);
    k_prep<<<(Nn * Dd / 8) / 256, 256, 0, stream>>>(f_pts, f8);   // after k1: f8 over Zpk
    k2_reduce<<<(Mm + 3) / 4, 256, 0, stream>>>(f8, cnt, rec, msgb);
    k3_mfma<<<(Mm / 16 + 3) / 4, 256, 0, stream>>>(z_lat, msgb, wsW, bg1, Wg2, bg2,
                                                   b_ih, b_hh, ln_g, ln_b, bd1, bd2,
                                                   Wd3, bd3, vacc, out);
}